// Round 19
// baseline (595.767 us; speedup 1.0000x reference)
//
#include <hip/hip_runtime.h>
#include <hip/hip_bf16.h>
#include <math.h>

#define HEADS 16
#define NCL 256
#define BB 8
#define NN 4096
#define DD 1024
#define DH 64
#define MM (BB*NN)   // 32768
#define KK 1024

typedef unsigned short u16;
typedef __attribute__((ext_vector_type(8))) short s8v;     // 8 bf16 (4 VGPRs)
typedef __attribute__((ext_vector_type(4))) float f32x4;   // MFMA C/D

__device__ __forceinline__ float bf2f(u16 u) {
    union { unsigned int i; float f; } v; v.i = ((unsigned int)u) << 16; return v.f;
}
__device__ __forceinline__ u16 f2bf(float x) {   // round-to-nearest-even
    union { float f; unsigned int i; } v; v.f = x;
    unsigned int u = v.i;
    return (u16)((u + 0x7FFFu + ((u >> 16) & 1u)) >> 16);
}
// pack hi16 halves of two f32 bit-patterns: low16 = a.hi16, high16 = b.hi16
__device__ __forceinline__ unsigned int pk2hi(unsigned int a, unsigned int b) {
    return __builtin_amdgcn_perm(b, a, 0x07060302);
}
__device__ __forceinline__ void gl16(const u16* g, u16* l) {
    __builtin_amdgcn_global_load_lds(
        (__attribute__((address_space(1))) void*)g,
        (__attribute__((address_space(3))) void*)l, 16, 0, 0);
}

// ---------------- fused prep: counts + tab + stable counting sort ----------
__global__ __launch_bounds__(256) void prep_k(const int* __restrict__ cluster,
                                              int* __restrict__ counts,
                                              float2* __restrict__ tab,
                                              int* __restrict__ tokidx,
                                              int* __restrict__ starts) {
    __shared__ int cl[NN];    // 16 KB
    __shared__ int pf[NCL];
    const int bb = blockIdx.x;
    const int tid = threadIdx.x;

    pf[tid] = 0;
    __syncthreads();
    for (int i = tid; i < NN; i += 256) {
        int c = cluster[bb * NN + i];
        cl[i] = c;
        atomicAdd(&pf[c], 1);
    }
    __syncthreads();

    const int myc = pf[tid];
    counts[bb * NCL + tid] = myc;
    float2 t;
    t.x = myc > 0 ? 0.125f / (float)myc : 0.f;
    t.y = (float)myc;
    tab[bb * NCL + tid] = t;

    for (int off = 1; off < NCL; off <<= 1) {
        int v = (tid >= off) ? pf[tid - off] : 0;
        __syncthreads();
        pf[tid] += v;
        __syncthreads();
    }
    int start = pf[tid] - myc;   // exclusive prefix
    starts[bb * NCL + tid] = start;

    int* dst = tokidx + bb * NN + start;
    int rank = 0;
    for (int t0 = 0; t0 < NN; t0 += 16) {
        int c16[16];
#pragma unroll
        for (int j = 0; j < 16; ++j) c16[j] = cl[t0 + j];   // batched reads
#pragma unroll
        for (int j = 0; j < 16; ++j) {
            if (c16[j] == tid) { dst[rank] = t0 + j; ++rank; }
        }
    }
}

// ---------------- weights (all 3): [K][N] fp32 -> [N][K] bf16 hi/lo --------
__global__ __launch_bounds__(256) void convw3_k(const float* __restrict__ wq,
                                                const float* __restrict__ wkv,
                                                const float* __restrict__ wproj,
                                                u16* __restrict__ thi,
                                                u16* __restrict__ tlo) {
    __shared__ float t[32][33];
    const int wz = blockIdx.z;
    const int bx = blockIdx.x, by = blockIdx.y;
    const int N = (wz == 1) ? 2048 : 1024;
    if (bx * 32 >= N) return;
    const float* w = (wz == 0) ? wq : (wz == 1) ? wkv : wproj;
    const size_t nbase = (wz == 0) ? 0 : (wz == 1) ? 1024 : 3072;
    const int lx = threadIdx.x & 31, ly = threadIdx.x >> 5;   // ly 0..7
#pragma unroll
    for (int p = 0; p < 4; ++p)
        t[p * 8 + ly][lx] = w[(size_t)(by * 32 + p * 8 + ly) * N + bx * 32 + lx];
    __syncthreads();
#pragma unroll
    for (int p = 0; p < 4; ++p) {
        size_t n = nbase + bx * 32 + p * 8 + ly;
        int k = by * 32 + lx;
        float v = t[lx][p * 8 + ly];
        u16 h = f2bf(v);
        thi[n * KK + k] = h;
        tlo[n * KK + k] = f2bf(v - bf2f(h));
    }
}

// ---------------- segment-sum of x via sorted index list (V path: hi/lo) ---
__global__ __launch_bounds__(256) void xsum2_k(const float* __restrict__ x,
                                               const int* __restrict__ tokidx,
                                               const int* __restrict__ starts,
                                               const int* __restrict__ counts,
                                               u16* __restrict__ shi,
                                               u16* __restrict__ slo) {
    const int bb = blockIdx.x >> 8;
    const int c = blockIdx.x & (NCL - 1);
    const int tid = threadIdx.x;
    const int start = starts[bb * NCL + c];
    const int cnt = counts[bb * NCL + c];
    const int* ti = tokidx + bb * NN + start;

    float a[4] = {0.f, 0.f, 0.f, 0.f};
    for (int i = 0; i < cnt; ++i) {
        int t = ti[i];
        const float* xr = x + ((size_t)bb * NN + t) * DD;
#pragma unroll
        for (int j = 0; j < 4; ++j) a[j] += xr[tid + 256 * j];
    }
    size_t o = ((size_t)bb * NCL + c) * DD;
#pragma unroll
    for (int j = 0; j < 4; ++j) {
        u16 h = f2bf(a[j]);
        shi[o + tid + 256 * j] = h;
        slo[o + tid + 256 * j] = f2bf(a[j] - bf2f(h));
    }
}

// ---------------- Csum -> K (single bf16) + V^T (hi/lo), fused -------------
// grid 128 (b*16+h), 256 thr. Part 1: K rows, pre-swizzled. Part 2: V^T via
// LDS transpose (convv body, its own syncs).
__global__ __launch_bounds__(256) void convkv_k(const float* __restrict__ Csum,
                                                u16* __restrict__ khi,
                                                u16* __restrict__ vthi,
                                                u16* __restrict__ vtlo) {
    __shared__ float vb[NCL][65];   // 66.5 KB
    const int bh = blockIdx.x;
    const int bb = bh >> 4, hh = bh & 15;
    const int tid = threadIdx.x;

    // ---- K part ----
#pragma unroll
    for (int i = 0; i < 8; ++i) {
        int ulin = tid + 256 * i;          // cl*8 + u
        int c = ulin >> 3, u = ulin & 7;
        const float* src = Csum + ((size_t)(bb * NCL + c)) * 2048 + hh * 64 + u * 8;
        float4 v0 = *(const float4*)src;
        float4 v1 = *(const float4*)(src + 4);
        size_t o = ((size_t)bh * NCL + c) * 64 + ((u ^ (c & 7)) << 3);
        ushort4 h0, h1;
        h0.x = f2bf(v0.x); h0.y = f2bf(v0.y); h0.z = f2bf(v0.z); h0.w = f2bf(v0.w);
        h1.x = f2bf(v1.x); h1.y = f2bf(v1.y); h1.z = f2bf(v1.z); h1.w = f2bf(v1.w);
        *(ushort4*)(khi + o) = h0; *(ushort4*)(khi + o + 4) = h1;
    }

    // ---- V part (transpose) ----
    const int d0 = tid & 63;
#pragma unroll
    for (int i = 0; i < 64; ++i) {
        int c = (tid >> 6) + i * 4;
        vb[c][d0] = Csum[((size_t)(bb * NCL + c)) * 2048 + 1024 + hh * 64 + d0];
    }
    __syncthreads();
    const int d = tid >> 2;
    const int uq = tid & 3;
#pragma unroll
    for (int j = 0; j < 8; ++j) {
        int u = uq * 8 + j;                // original unit (8 clusters)
        int c0 = u * 8;
        float v[8];
#pragma unroll
        for (int e = 0; e < 8; ++e) v[e] = vb[c0 + e][d];
        ushort4 h0, l0, h1, l1;
        h0.x = f2bf(v[0]); l0.x = f2bf(v[0] - bf2f(h0.x));
        h0.y = f2bf(v[1]); l0.y = f2bf(v[1] - bf2f(h0.y));
        h0.z = f2bf(v[2]); l0.z = f2bf(v[2] - bf2f(h0.z));
        h0.w = f2bf(v[3]); l0.w = f2bf(v[3] - bf2f(h0.w));
        h1.x = f2bf(v[4]); l1.x = f2bf(v[4] - bf2f(h1.x));
        h1.y = f2bf(v[5]); l1.y = f2bf(v[5] - bf2f(h1.y));
        h1.z = f2bf(v[6]); l1.z = f2bf(v[6] - bf2f(h1.z));
        h1.w = f2bf(v[7]); l1.w = f2bf(v[7] - bf2f(h1.w));
        int usw = (u & 24) | ((u ^ d) & 7);  // low3 bits XOR'd within 8-group
        size_t o = ((size_t)bh * 64 + d) * 256 + usw * 8;
        *(ushort4*)(vthi + o) = h0; *(ushort4*)(vthi + o + 4) = h1;
        *(ushort4*)(vtlo + o) = l0; *(ushort4*)(vtlo + o + 4) = l1;
    }
}

// ---------------- 128-tile split-bf16 GEMM (kept for the small Csum GEMM) --
template<int OUT>
__global__ __launch_bounds__(256) void hgemm_k(
        const u16* __restrict__ Ahi, const u16* __restrict__ Alo,
        const u16* __restrict__ Bhi, const u16* __restrict__ Blo,
        float* __restrict__ C, int ldc, const float* __restrict__ bias,
        u16* __restrict__ Ohi, u16* __restrict__ Olo) {
    __shared__ u16 sh[4][128 * 32];

    const int tid = threadIdx.x;
    const int lane = tid & 63;
    const int wid = tid >> 6;
    const int wm = wid >> 1, wn = wid & 1;
    const size_t row0 = (size_t)blockIdx.y * 128;
    const size_t col0 = (size_t)blockIdx.x * 128;

    const int sr = tid >> 2;
    const int sq = tid & 3;
    const int qs = sq ^ ((sr >> 1) & 3);

    const u16* ga0 = Ahi + (row0 + sr) * KK + qs * 8;
    const u16* ga1 = ga0 + (size_t)64 * KK;
    const u16* gA0 = Alo + (row0 + sr) * KK + qs * 8;
    const u16* gA1 = gA0 + (size_t)64 * KK;
    const u16* gb0 = Bhi + (col0 + sr) * KK + qs * 8;
    const u16* gb1 = gb0 + (size_t)64 * KK;
    const u16* gB0 = Blo + (col0 + sr) * KK + qs * 8;
    const u16* gB1 = gB0 + (size_t)64 * KK;

    u16* d = (u16*)sh + tid * 8;

    const int rA = wm * 64 + (lane & 15);
    const int rB = wn * 64 + (lane & 15);
    const int aoff = rA * 32 + (((lane >> 4) ^ ((rA >> 1) & 3)) * 8);
    const int boff = rB * 32 + (((lane >> 4) ^ ((rB >> 1) & 3)) * 8);

    f32x4 acc[4][4] = {};

    for (int k0 = 0; k0 < KK; k0 += 32) {
        gl16(ga0 + k0, d);
        gl16(ga1 + k0, d + 2048);
        gl16(gA0 + k0, d + 4096);
        gl16(gA1 + k0, d + 6144);
        gl16(gb0 + k0, d + 8192);
        gl16(gb1 + k0, d + 10240);
        gl16(gB0 + k0, d + 12288);
        gl16(gB1 + k0, d + 14336);
        __syncthreads();
        s8v ah[4], al[4], bh[4], bl[4];
#pragma unroll
        for (int i = 0; i < 4; ++i) {
            ah[i] = *(const s8v*)&sh[0][aoff + i * 512];
            al[i] = *(const s8v*)&sh[1][aoff + i * 512];
            bh[i] = *(const s8v*)&sh[2][boff + i * 512];
            bl[i] = *(const s8v*)&sh[3][boff + i * 512];
        }
#pragma unroll
        for (int i = 0; i < 4; ++i)
#pragma unroll
            for (int j = 0; j < 4; ++j) {
                acc[i][j] = __builtin_amdgcn_mfma_f32_16x16x32_bf16(ah[i], bh[j], acc[i][j], 0, 0, 0);
                acc[i][j] = __builtin_amdgcn_mfma_f32_16x16x32_bf16(ah[i], bl[j], acc[i][j], 0, 0, 0);
                acc[i][j] = __builtin_amdgcn_mfma_f32_16x16x32_bf16(al[i], bh[j], acc[i][j], 0, 0, 0);
            }
        __syncthreads();
    }

    const int fr = (lane >> 4) * 4;
    const int fc = lane & 15;

    float bj[4] = {0.f, 0.f, 0.f, 0.f};
    if constexpr (OUT == 1) {
#pragma unroll
        for (int j = 0; j < 4; ++j) bj[j] = bias[col0 + wn * 64 + j * 16 + fc];
    }
#pragma unroll
    for (int i = 0; i < 4; ++i)
#pragma unroll
        for (int j = 0; j < 4; ++j) {
            size_t rbase = row0 + wm * 64 + i * 16 + fr;
            size_t cidx = col0 + wn * 64 + j * 16 + fc;
#pragma unroll
            for (int g = 0; g < 4; ++g)
                C[(rbase + g) * (size_t)ldc + cidx] = acc[i][j][g] + bj[j];
        }
}

// ---------------- Q-GEMM: fp32-A staged, single-bf16 (R19 fused convx) -----
// Q = X @ Wq^T: A = x fp32 staged via gl16 (pre-swizzled source, linear
// dest — rule 21), converted to bf16 by truncation (v_perm) after the LDS
// read; B = Wq^T hi (bf16). Barrier-light loop. LDS 96 KB.
// A swizzle: unit u (16B of 4 fp32) of row r stored at slot u ^ ((r>>2)&1)
// -> 16-lane read groups span 8 distinct bank-quads (2-way = free).
__global__ __launch_bounds__(512) void qgemm_k(const float* __restrict__ X,
                                               const u16* __restrict__ Bhi,
                                               u16* __restrict__ Ohi) {
    __shared__ u16 sh2[2][24576];   // per buf: A fp32 32 KB | Bhi 16 KB

    const int tid = threadIdx.x;
    const int lane = tid & 63;
    const int wid = tid >> 6;
    const int wm = wid >> 2, wn = wid & 3;
    const int l15 = lane & 15;
    const int g = lane >> 4;

    const int nwg = gridDim.x;
    const int cpx = nwg >> 3;
    const int lin = blockIdx.x;
    const int swz = (lin & 7) * cpx + (lin >> 3);
    const int bx = swz & 3;          // N = 1024 -> 4 col tiles
    const int by = swz >> 2;

    const size_t row0 = (size_t)by * 256;
    const size_t col0 = (size_t)bx * 256;

    // A staging: thread -> row ra (0..255), pair pa; 4 calls cover 8 units.
    const int ra = tid >> 1;
    const int pa = tid & 1;
    const int swra = (ra >> 2) & 1;
    const float* pX[4];
#pragma unroll
    for (int c = 0; c < 4; ++c)
        pX[c] = X + (row0 + ra) * 1024 + (((2 * c + pa) ^ swra) * 4);

    // B staging (identical to R18 SGL layout)
    const int sr0 = tid >> 2;
    const int qs0 = (tid & 3) ^ ((sr0 >> 1) & 3);
    const u16* pBh0 = Bhi + (col0 + sr0) * KK + qs0 * 8;
    const u16* pBh1 = pBh0 + (size_t)128 * KK;

#define QSTG(bw, k) {                                                          \
        u16* ab = sh2[bw];                                                     \
        gl16((const u16*)(pX[0] + (k)), ab + tid * 8);                         \
        gl16((const u16*)(pX[1] + (k)), ab + 4096 + tid * 8);                  \
        gl16((const u16*)(pX[2] + (k)), ab + 8192 + tid * 8);                  \
        gl16((const u16*)(pX[3] + (k)), ab + 12288 + tid * 8);                 \
        u16* db = ab + 16384 + tid * 8;                                        \
        gl16(pBh0 + (k), db);  gl16(pBh1 + (k), db + 4096); }

    const int rB = wn * 64 + l15;
    const int boff = rB * 32 + (((lane >> 4) ^ ((rB >> 1) & 3)) * 8);
    const int swl = (l15 >> 2) & 1;
    // A read byte base (within A area): page g*8192 + row*32 + swl*16
    const int abyte = g * 8192 + (wm * 128 + l15) * 32 + swl * 16;

    f32x4 acc[8][4] = {};

    QSTG(0, 0);
    __syncthreads();

    int cur = 0;
    for (int kt = 0; kt < 32; ++kt) {
        const int kn = (kt + 1) * 32;
        const char* Ab = (const char*)sh2[cur];
        const u16* Bb = sh2[cur] + 16384;
        const int bw = cur ^ 1;
        if (kt < 31) QSTG(bw, kn);

        s8v bhf[4];
#pragma unroll
        for (int ni = 0; ni < 4; ++ni)
            bhf[ni] = *(const s8v*)(Bb + boff + ni * 512);

        s8v ahf[8];
#pragma unroll
        for (int mi = 0; mi < 8; ++mi) {
            int b0 = abyte + mi * 512;
            f32x4 flo = *(const f32x4*)(Ab + b0);
            f32x4 fhi = *(const f32x4*)(Ab + (b0 ^ 16));
            uint4 q;
            q.x = pk2hi(__float_as_uint(flo[0]), __float_as_uint(flo[1]));
            q.y = pk2hi(__float_as_uint(flo[2]), __float_as_uint(flo[3]));
            q.z = pk2hi(__float_as_uint(fhi[0]), __float_as_uint(fhi[1]));
            q.w = pk2hi(__float_as_uint(fhi[2]), __float_as_uint(fhi[3]));
            union { uint4 u; s8v s; } cv; cv.u = q;
            ahf[mi] = cv.s;
        }

        __builtin_amdgcn_s_setprio(1);
#pragma unroll
        for (int mi = 0; mi < 8; ++mi)
#pragma unroll
            for (int ni = 0; ni < 4; ++ni)
                acc[mi][ni] = __builtin_amdgcn_mfma_f32_16x16x32_bf16(ahf[mi], bhf[ni], acc[mi][ni], 0, 0, 0);
        __builtin_amdgcn_s_setprio(0);
        __syncthreads();
        cur ^= 1;
    }
#undef QSTG

    const int fr = (lane >> 4) * 4;
    const int fc = lane & 15;
#pragma unroll
    for (int mi = 0; mi < 8; ++mi)
#pragma unroll
        for (int ni = 0; ni < 4; ++ni) {
            size_t rbase = row0 + wm * 128 + mi * 16 + fr;
            size_t cidx = col0 + wn * 64 + ni * 16 + fc;
#pragma unroll
            for (int g2 = 0; g2 < 4; ++g2)
                Ohi[(rbase + g2) * 1024 + cidx] = f2bf(acc[mi][ni][g2]);
        }
}

// ---------------- 256-tile 8-wave phased split-bf16 GEMM (R13, out-proj) ---
template<int OUT, int SGL>
__global__ __launch_bounds__(512) void hgemm256_k(
        const u16* __restrict__ Ahi, const u16* __restrict__ Alo,
        const u16* __restrict__ Bhi, const u16* __restrict__ Blo,
        float* __restrict__ C, int ldc, const float* __restrict__ bias,
        u16* __restrict__ Ohi, u16* __restrict__ Olo) {
    __shared__ u16 sh[2][4][8192];   // [buf][Ahi|Alo|Bhi|Blo][256*32]

    const int tid = threadIdx.x;
    const int lane = tid & 63;
    const int wid = tid >> 6;
    const int wm = wid >> 2, wn = wid & 3;
    const int l15 = lane & 15;

    const int nwg = gridDim.x;
    const int cpx = nwg >> 3;
    const int lin = blockIdx.x;
    const int swz = (lin & 7) * cpx + (lin >> 3);
    const int bx = swz & 3;          // N = 1024 -> 4 col tiles
    const int by = swz >> 2;

    const size_t row0 = (size_t)by * 256;
    const size_t col0 = (size_t)bx * 256;

    const int sr0 = tid >> 2;            // 0..127
    const int qs0 = (tid & 3) ^ ((sr0 >> 1) & 3);
    const u16* pAh0 = Ahi + (row0 + sr0) * KK + qs0 * 8;
    const u16* pAh1 = pAh0 + (size_t)128 * KK;
    const u16* pAl0 = Alo + (row0 + sr0) * KK + qs0 * 8;
    const u16* pAl1 = pAl0 + (size_t)128 * KK;
    const u16* pBh0 = Bhi + (col0 + sr0) * KK + qs0 * 8;
    const u16* pBh1 = pBh0 + (size_t)128 * KK;
    const u16* pBl0 = Blo + (col0 + sr0) * KK + qs0 * 8;
    const u16* pBl1 = pBl0 + (size_t)128 * KK;

#define STG_A(bw, k) { u16* db = (u16*)sh + (bw) * 32768 + tid * 8;            \
        gl16(pAh0 + (k), db);            gl16(pAh1 + (k), db + 4096);          \
        if constexpr (!SGL) {                                                  \
            gl16(pAl0 + (k), db + 8192); gl16(pAl1 + (k), db + 12288); } }
#define STG_B(bw, k) { u16* db = (u16*)sh + (bw) * 32768 + 16384 + tid * 8;    \
        gl16(pBh0 + (k), db);            gl16(pBh1 + (k), db + 4096);          \
        if constexpr (!SGL) {                                                  \
            gl16(pBl0 + (k), db + 8192); gl16(pBl1 + (k), db + 12288); } }

    const int rA = wm * 128 + l15;
    const int rB = wn * 64 + l15;
    const int aoff = rA * 32 + (((lane >> 4) ^ ((rA >> 1) & 3)) * 8);
    const int boff = rB * 32 + (((lane >> 4) ^ ((rB >> 1) & 3)) * 8);

    f32x4 acc[8][4] = {};

    STG_A(0, 0);
    STG_B(0, 0);
    __syncthreads();

    int cur = 0;
    for (int kt = 0; kt < 32; ++kt) {
        const int kn = (kt + 1) * 32;
        const u16* br = (const u16*)sh + cur * 32768;
        const int bw = cur ^ 1;
        const bool st = kt < 31;

        if (st) STG_A(bw, kn);
        s8v bhf[4], blf[4];
#pragma unroll
        for (int ni = 0; ni < 4; ++ni) {
            bhf[ni] = *(const s8v*)(br + 16384 + boff + ni * 512);
            blf[ni] = *(const s8v*)(br + 24576 + boff + ni * 512);
        }
        {
            s8v ah0 = *(const s8v*)(br + aoff);
            s8v al0 = *(const s8v*)(br + 8192 + aoff);
            s8v ah1 = *(const s8v*)(br + aoff + 512);
            s8v al1 = *(const s8v*)(br + 8192 + aoff + 512);
            __builtin_amdgcn_s_setprio(1);
#pragma unroll
            for (int ni = 0; ni < 4; ++ni) {
                acc[0][ni] = __builtin_amdgcn_mfma_f32_16x16x32_bf16(ah0, bhf[ni], acc[0][ni], 0, 0, 0);
                acc[0][ni] = __builtin_amdgcn_mfma_f32_16x16x32_bf16(ah0, blf[ni], acc[0][ni], 0, 0, 0);
                acc[0][ni] = __builtin_amdgcn_mfma_f32_16x16x32_bf16(al0, bhf[ni], acc[0][ni], 0, 0, 0);
                acc[1][ni] = __builtin_amdgcn_mfma_f32_16x16x32_bf16(ah1, bhf[ni], acc[1][ni], 0, 0, 0);
                acc[1][ni] = __builtin_amdgcn_mfma_f32_16x16x32_bf16(ah1, blf[ni], acc[1][ni], 0, 0, 0);
                acc[1][ni] = __builtin_amdgcn_mfma_f32_16x16x32_bf16(al1, bhf[ni], acc[1][ni], 0, 0, 0);
            }
            __builtin_amdgcn_s_setprio(0);
        }
        __builtin_amdgcn_s_barrier();

#pragma unroll
        for (int p = 1; p < 4; ++p) {
            if (p == 1 && st) STG_B(bw, kn);
            const int m0 = 2 * p;
            s8v ah0 = *(const s8v*)(br + aoff + m0 * 512);
            s8v al0 = *(const s8v*)(br + 8192 + aoff + m0 * 512);
            s8v ah1 = *(const s8v*)(br + aoff + (m0 + 1) * 512);
            s8v al1 = *(const s8v*)(br + 8192 + aoff + (m0 + 1) * 512);
            __builtin_amdgcn_s_setprio(1);
#pragma unroll
            for (int ni = 0; ni < 4; ++ni) {
                acc[m0][ni] = __builtin_amdgcn_mfma_f32_16x16x32_bf16(ah0, bhf[ni], acc[m0][ni], 0, 0, 0);
                acc[m0][ni] = __builtin_amdgcn_mfma_f32_16x16x32_bf16(ah0, blf[ni], acc[m0][ni], 0, 0, 0);
                acc[m0][ni] = __builtin_amdgcn_mfma_f32_16x16x32_bf16(al0, bhf[ni], acc[m0][ni], 0, 0, 0);
                acc[m0 + 1][ni] = __builtin_amdgcn_mfma_f32_16x16x32_bf16(ah1, bhf[ni], acc[m0 + 1][ni], 0, 0, 0);
                acc[m0 + 1][ni] = __builtin_amdgcn_mfma_f32_16x16x32_bf16(ah1, blf[ni], acc[m0 + 1][ni], 0, 0, 0);
                acc[m0 + 1][ni] = __builtin_amdgcn_mfma_f32_16x16x32_bf16(al1, bhf[ni], acc[m0 + 1][ni], 0, 0, 0);
            }
            __builtin_amdgcn_s_setprio(0);
            if (p < 3) __builtin_amdgcn_s_barrier();
        }

        __syncthreads();
        cur ^= 1;
    }
#undef STG_A
#undef STG_B

    const int fr = (lane >> 4) * 4;
    const int fc = lane & 15;

    if constexpr (OUT == 2) {
#pragma unroll
        for (int mi = 0; mi < 8; ++mi)
#pragma unroll
            for (int ni = 0; ni < 4; ++ni) {
                size_t rbase = row0 + wm * 128 + mi * 16 + fr;
                size_t cidx = col0 + wn * 64 + ni * 16 + fc;
#pragma unroll
                for (int g = 0; g < 4; ++g) {
                    float o = acc[mi][ni][g];
                    u16 h = f2bf(o);
                    size_t idx = (rbase + g) * 1024 + cidx;
                    Ohi[idx] = h;
                    if constexpr (!SGL) {
                        Olo[idx] = f2bf(o - bf2f(h));
                    }
                }
            }
    } else {
        float bj[4];
#pragma unroll
        for (int ni = 0; ni < 4; ++ni) bj[ni] = bias[col0 + wn * 64 + ni * 16 + fc];
#pragma unroll
        for (int mi = 0; mi < 8; ++mi)
#pragma unroll
            for (int ni = 0; ni < 4; ++ni) {
                size_t rbase = row0 + wm * 128 + mi * 16 + fr;
                size_t cidx = col0 + wn * 64 + ni * 16 + fc;
#pragma unroll
                for (int g = 0; g < 4; ++g)
                    C[(rbase + g) * (size_t)ldc + cidx] = acc[mi][ni][g] + bj[ni];
            }
    }
}

// ---------------- fused MFMA attention (R17, unchanged) --------------------
__global__ __launch_bounds__(256) void fattn_k(const u16* __restrict__ Qhi,
                                               const u16* __restrict__ Khi,
                                               const u16* __restrict__ Vthi,
                                               const u16* __restrict__ Vtlo,
                                               const float2* __restrict__ tab,
                                               u16* __restrict__ Phi,
                                               u16* __restrict__ Plo) {
    __shared__ u16 qh[64 * 64];      // 8 KB  [tok][unit^(tok&7) * 8]
    __shared__ u16 zb[16 * 512];     // 16 KB [(w*4+cf)*512 + lane*8 + e]
    __shared__ float lpart[4][64];
    __shared__ float invl[64];

    const int tid = threadIdx.x;
    const int lane = tid & 63;
    const int w = tid >> 6;
    const int g = lane >> 4;
    const int l15 = lane & 15;
    const int hh = blockIdx.y, bb = blockIdx.z;
    const int bh = bb * 16 + hh;
    const int tok0 = blockIdx.x * 64;

    // ---- stage Q into LDS (source pre-swizzled; dest linear) ----
#pragma unroll
    for (int i = 0; i < 2; ++i) {
        int ulin = tid + 256 * i;          // tok*8 + u'
        int tok = ulin >> 3, up = ulin & 7;
        size_t src = ((size_t)(bb * NN + tok0 + tok)) * 1024 + hh * 64
                     + ((up ^ (tok & 7)) << 3);
        gl16(Qhi + src, qh + ulin * 8);
    }
    __syncthreads();

    const size_t kbase = (size_t)bh * NCL * 64;
    const size_t vbase = (size_t)bh * 64 * 256;
    const int dg = w * 16 + l15;

    float lp[4] = {0.f, 0.f, 0.f, 0.f};
    f32x4 oacc[4] = {};

#pragma unroll
    for (int h = 0; h < 2; ++h) {
        // ---- QK^T for f in {2h, 2h+1} (single-bf16 both operands) ----
        f32x4 acch[2][4] = {};
#pragma unroll
        for (int ff = 0; ff < 2; ++ff) {
            const int f = 2 * h + ff;
            const int cl = w * 64 + f * 16 + l15;
            s8v kf[2];
#pragma unroll
            for (int ks = 0; ks < 2; ++ks) {
                size_t ko = kbase + (size_t)cl * 64 + (((ks * 4 + g) ^ (l15 & 7)) << 3);
                kf[ks] = *(const s8v*)(Khi + ko);
            }
#pragma unroll
            for (int cf = 0; cf < 4; ++cf) {
                const int qr = cf * 16 + l15;   // token row in LDS
#pragma unroll
                for (int ks = 0; ks < 2; ++ks) {
                    int qa = qr * 64 + (((ks * 4 + g) ^ (qr & 7)) << 3);
                    s8v qfh = *(const s8v*)&qh[qa];
                    acch[ff][cf] = __builtin_amdgcn_mfma_f32_16x16x32_bf16(kf[ks], qfh, acch[ff][cf], 0, 0, 0);
                }
            }
        }

        // ---- softmax weights -> read-linear z (single RNE bf16) ----
#pragma unroll
        for (int ff = 0; ff < 2; ++ff) {
            const int f = 2 * h + ff;
            float2 t4[4];
#pragma unroll
            for (int r = 0; r < 4; ++r)
                t4[r] = tab[bb * NCL + w * 64 + f * 16 + 4 * g + r];
#pragma unroll
            for (int cf = 0; cf < 4; ++cf) {
                float z[4];
#pragma unroll
                for (int r = 0; r < 4; ++r) {
                    float e = __expf(acch[ff][cf][r] * t4[r].x);
                    lp[cf] += t4[r].y * e;
                    z[r] = t4[r].y > 0.f ? e : 0.f;
                }
                uint2 pz;
                pz.x = (unsigned int)f2bf(z[0]) | ((unsigned int)f2bf(z[1]) << 16);
                pz.y = (unsigned int)f2bf(z[2]) | ((unsigned int)f2bf(z[3]) << 16);
                int a16 = (w * 4 + cf) * 512
                          + ((2 * ff + (g >> 1)) * 16 + l15) * 8 + 4 * (g & 1);
                *(uint2*)&zb[a16] = pz;
            }
        }

        if (h == 1) {
#pragma unroll
            for (int cf = 0; cf < 4; ++cf) {
                float v = lp[cf];
                v += __shfl_xor(v, 16);
                v += __shfl_xor(v, 32);
                lp[cf] = v;
            }
            if (lane < 16) {
#pragma unroll
                for (int cf = 0; cf < 4; ++cf) lpart[w][cf * 16 + lane] = lp[cf];
            }
        }
        __syncthreads();   // z half ready (h=1: + lpart ready)

        if (h == 1 && w == 0)
            invl[lane] = 1.f / (lpart[0][lane] + lpart[1][lane] + lpart[2][lane] + lpart[3][lane]);

        // ---- PV for this half: ks = 2s+h, z chunk = s*4+cf (2 MFMA) ----
#pragma unroll
        for (int s = 0; s < 4; ++s) {
            int kst = 2 * s + h;
            size_t vo = vbase + (size_t)dg * 256
                        + (((kst * 4 + g) & 24) | (((kst * 4 + g) ^ dg) & 7)) * 8;
            s8v vh = *(const s8v*)(Vthi + vo);
            s8v vl = *(const s8v*)(Vtlo + vo);
#pragma unroll
            for (int cf = 0; cf < 4; ++cf) {
                int a16 = (s * 4 + cf) * 512 + lane * 8;
                s8v zf = *(const s8v*)&zb[a16];
                oacc[cf] = __builtin_amdgcn_mfma_f32_16x16x32_bf16(vh, zf, oacc[cf], 0, 0, 0);
                oacc[cf] = __builtin_amdgcn_mfma_f32_16x16x32_bf16(vl, zf, oacc[cf], 0, 0, 0);
            }
        }
        __syncthreads();   // z reads done (h=0) / invl ready (h=1)
    }

    // ---- epilogue: scale by 1/l, trunc hi/lo pack, store ----
#pragma unroll
    for (int cf = 0; cf < 4; ++cf) {
        const int tokL = cf * 16 + l15;
        float il = invl[tokL];
        float o0 = oacc[cf][0] * il, o1 = oacc[cf][1] * il;
        float o2 = oacc[cf][2] * il, o3 = oacc[cf][3] * il;
        unsigned int b0 = __float_as_uint(o0), b1 = __float_as_uint(o1);
        unsigned int b2 = __float_as_uint(o2), b3 = __float_as_uint(o3);
        float r0 = o0 - __uint_as_float(b0 & 0xFFFF0000u);
        float r1 = o1 - __uint_as_float(b1 & 0xFFFF0000u);
        float r2 = o2 - __uint_as_float(b2 & 0xFFFF0000u);
        float r3 = o3 - __uint_as_float(b3 & 0xFFFF0000u);
        uint2 ph, pl;
        ph.x = pk2hi(b0, b1); ph.y = pk2hi(b2, b3);
        pl.x = pk2hi(__float_as_uint(r0), __float_as_uint(r1));
        pl.y = pk2hi(__float_as_uint(r2), __float_as_uint(r3));
        size_t po = ((size_t)(bb * NN + tok0 + tokL)) * 1024 + hh * 64 + w * 16 + 4 * g;
        *(uint2*)(Phi + po) = ph;
        *(uint2*)(Plo + po) = pl;
    }
}

// ---------------- launcher -------------------------------------------------
extern "C" void kernel_launch(void* const* d_in, const int* in_sizes, int n_in,
                              void* d_out, int out_size, void* d_ws, size_t ws_size,
                              hipStream_t stream) {
    const int* cluster  = (const int*)d_in[0];
    const float* x      = (const float*)d_in[1];
    const float* w_q    = (const float*)d_in[2];
    const float* w_kv   = (const float*)d_in[3];
    const float* w_proj = (const float*)d_in[4];
    const float* b_proj = (const float*)d_in[5];
    float* out = (float*)d_out;

    // layout (~312 MiB)
    const size_t SZ_H  = (size_t)MM * 1024 * 2;      // 64 MiB
    const size_t SZ_W  = (size_t)4096 * 1024 * 2;    // 8 MiB
    const size_t SZ_XS = (size_t)2048 * 1024 * 2;    // 4 MiB
    const size_t SZ_CS = (size_t)2048 * 2048 * 4;    // 16 MiB
    const size_t SZ_KV = (size_t)128 * NCL * 64 * 2; // 4 MiB

    char* p = (char*)d_ws;
    u16* Xhi = (u16*)p;   p += SZ_H;    // Phi (fattn out / out-proj A hi)
    u16* Xlo = (u16*)p;   p += SZ_H;    // Plo
    u16* Qhi = (u16*)p;   p += SZ_H;
    u16* Qlo = (u16*)p;   p += SZ_H;    // unused (layout stability)
    u16* Wthi = (u16*)p;  p += SZ_W;
    u16* Wtlo = (u16*)p;  p += SZ_W;
    u16* XShi = (u16*)p;  p += SZ_XS;
    u16* XSlo = (u16*)p;  p += SZ_XS;
    float* Csum = (float*)p; p += SZ_CS;
    u16* Khi = (u16*)p;   p += SZ_KV;
    u16* Klo = (u16*)p;   p += SZ_KV;   // unused
    u16* Vthi = (u16*)p;  p += SZ_KV;
    u16* Vtlo = (u16*)p;  p += SZ_KV;
    float2* tab = (float2*)p; p += 2048 * sizeof(float2);
    int* counts = (int*)p;   p += 2048 * sizeof(int);
    int* tokidx = (int*)p;   p += (size_t)BB * NN * sizeof(int);
    int* starts = (int*)p;
    (void)Klo; (void)Qlo;

    // fused prep: counts + tab + stable counting sort
    prep_k<<<BB, 256, 0, stream>>>(cluster, counts, tab, tokidx, starts);

    convw3_k<<<dim3(64, 32, 3), 256, 0, stream>>>(w_q, w_kv, w_proj, Wthi, Wtlo);

    xsum2_k<<<BB * NCL, 256, 0, stream>>>(x, tokidx, starts, counts, XShi, XSlo);

    // Q = X(fp32, staged+converted in-kernel) @ Wq^T(hi) -> Qhi
    qgemm_k<<<512, 512, 0, stream>>>(x, Wthi, Qhi);

    // Csum = XS @ Wkv^T (ksum | vsum), fp32 (full hi/lo: V path)
    hgemm_k<0><<<dim3(16, 16), 256, 0, stream>>>(XShi, XSlo,
                                                 Wthi + (size_t)1024 * KK, Wtlo + (size_t)1024 * KK,
                                                 Csum, 2048, nullptr, nullptr, nullptr);
    // K (single bf16) + V^T (hi/lo), fused conversion
    convkv_k<<<128, 256, 0, stream>>>(Csum, Khi, Vthi, Vtlo);

    // fused attention -> P (bf16 hi/lo, aliases X buffers); 64-tok blocks
    fattn_k<<<dim3(NN / 64, HEADS, BB), 256, 0, stream>>>(Qhi, Khi,
                                                          Vthi, Vtlo, tab, Xhi, Xlo);
    // out = P @ Wproj^T + bias (full hi/lo: R13 4-phase schedule)
    hgemm256_k<1, 0><<<512, 512, 0, stream>>>(Xhi, Xlo,
                                              Wthi + (size_t)3072 * KK, Wtlo + (size_t)3072 * KK,
                                              out, 1024, b_proj, nullptr, nullptr);
}

// Round 20
// 581.173 us; speedup vs baseline: 1.0251x; 1.0251x over previous
//
#include <hip/hip_runtime.h>
#include <hip/hip_bf16.h>
#include <math.h>

#define HEADS 16
#define NCL 256
#define BB 8
#define NN 4096
#define DD 1024
#define DH 64
#define MM (BB*NN)   // 32768
#define KK 1024

typedef unsigned short u16;
typedef __attribute__((ext_vector_type(8))) short s8v;     // 8 bf16 (4 VGPRs)
typedef __attribute__((ext_vector_type(4))) float f32x4;   // MFMA C/D

__device__ __forceinline__ float bf2f(u16 u) {
    union { unsigned int i; float f; } v; v.i = ((unsigned int)u) << 16; return v.f;
}
__device__ __forceinline__ u16 f2bf(float x) {   // round-to-nearest-even
    union { float f; unsigned int i; } v; v.f = x;
    unsigned int u = v.i;
    return (u16)((u + 0x7FFFu + ((u >> 16) & 1u)) >> 16);
}
// pack hi16 halves of two f32 bit-patterns: low16 = a.hi16, high16 = b.hi16
__device__ __forceinline__ unsigned int pk2hi(unsigned int a, unsigned int b) {
    return __builtin_amdgcn_perm(b, a, 0x07060302);
}
__device__ __forceinline__ void gl16(const u16* g, u16* l) {
    __builtin_amdgcn_global_load_lds(
        (__attribute__((address_space(1))) void*)g,
        (__attribute__((address_space(3))) void*)l, 16, 0, 0);
}

// ---------------- fused prep: counts + tab + stable counting sort ----------
__global__ __launch_bounds__(256) void prep_k(const int* __restrict__ cluster,
                                              int* __restrict__ counts,
                                              float2* __restrict__ tab,
                                              int* __restrict__ tokidx,
                                              int* __restrict__ starts) {
    __shared__ int cl[NN];    // 16 KB
    __shared__ int pf[NCL];
    const int bb = blockIdx.x;
    const int tid = threadIdx.x;

    pf[tid] = 0;
    __syncthreads();
    for (int i = tid; i < NN; i += 256) {
        int c = cluster[bb * NN + i];
        cl[i] = c;
        atomicAdd(&pf[c], 1);
    }
    __syncthreads();

    const int myc = pf[tid];
    counts[bb * NCL + tid] = myc;
    float2 t;
    t.x = myc > 0 ? 0.125f / (float)myc : 0.f;
    t.y = (float)myc;
    tab[bb * NCL + tid] = t;

    for (int off = 1; off < NCL; off <<= 1) {
        int v = (tid >= off) ? pf[tid - off] : 0;
        __syncthreads();
        pf[tid] += v;
        __syncthreads();
    }
    int start = pf[tid] - myc;   // exclusive prefix
    starts[bb * NCL + tid] = start;

    int* dst = tokidx + bb * NN + start;
    int rank = 0;
    for (int t0 = 0; t0 < NN; t0 += 16) {
        int c16[16];
#pragma unroll
        for (int j = 0; j < 16; ++j) c16[j] = cl[t0 + j];   // batched reads
#pragma unroll
        for (int j = 0; j < 16; ++j) {
            if (c16[j] == tid) { dst[rank] = t0 + j; ++rank; }
        }
    }
}

// ---------------- x -> single bf16 (score path) ----------------------------
__global__ __launch_bounds__(256) void convx1_k(const float* __restrict__ x,
                                                u16* __restrict__ hi) {
    size_t i = ((size_t)blockIdx.x * 256 + threadIdx.x) * 4;
    float4 v = *(const float4*)(x + i);
    ushort4 h;
    h.x = f2bf(v.x); h.y = f2bf(v.y); h.z = f2bf(v.z); h.w = f2bf(v.w);
    *(ushort4*)(hi + i) = h;
}

// ---------------- weights (all 3): [K][N] fp32 -> [N][K] bf16 hi/lo --------
__global__ __launch_bounds__(256) void convw3_k(const float* __restrict__ wq,
                                                const float* __restrict__ wkv,
                                                const float* __restrict__ wproj,
                                                u16* __restrict__ thi,
                                                u16* __restrict__ tlo) {
    __shared__ float t[32][33];
    const int wz = blockIdx.z;
    const int bx = blockIdx.x, by = blockIdx.y;
    const int N = (wz == 1) ? 2048 : 1024;
    if (bx * 32 >= N) return;
    const float* w = (wz == 0) ? wq : (wz == 1) ? wkv : wproj;
    const size_t nbase = (wz == 0) ? 0 : (wz == 1) ? 1024 : 3072;
    const int lx = threadIdx.x & 31, ly = threadIdx.x >> 5;   // ly 0..7
#pragma unroll
    for (int p = 0; p < 4; ++p)
        t[p * 8 + ly][lx] = w[(size_t)(by * 32 + p * 8 + ly) * N + bx * 32 + lx];
    __syncthreads();
#pragma unroll
    for (int p = 0; p < 4; ++p) {
        size_t n = nbase + bx * 32 + p * 8 + ly;
        int k = by * 32 + lx;
        float v = t[lx][p * 8 + ly];
        u16 h = f2bf(v);
        thi[n * KK + k] = h;
        tlo[n * KK + k] = f2bf(v - bf2f(h));
    }
}

// ---------------- segment-sum of x via sorted index list (V path: hi/lo) ---
__global__ __launch_bounds__(256) void xsum2_k(const float* __restrict__ x,
                                               const int* __restrict__ tokidx,
                                               const int* __restrict__ starts,
                                               const int* __restrict__ counts,
                                               u16* __restrict__ shi,
                                               u16* __restrict__ slo) {
    const int bb = blockIdx.x >> 8;
    const int c = blockIdx.x & (NCL - 1);
    const int tid = threadIdx.x;
    const int start = starts[bb * NCL + c];
    const int cnt = counts[bb * NCL + c];
    const int* ti = tokidx + bb * NN + start;

    float a[4] = {0.f, 0.f, 0.f, 0.f};
    for (int i = 0; i < cnt; ++i) {
        int t = ti[i];
        const float* xr = x + ((size_t)bb * NN + t) * DD;
#pragma unroll
        for (int j = 0; j < 4; ++j) a[j] += xr[tid + 256 * j];
    }
    size_t o = ((size_t)bb * NCL + c) * DD;
#pragma unroll
    for (int j = 0; j < 4; ++j) {
        u16 h = f2bf(a[j]);
        shi[o + tid + 256 * j] = h;
        slo[o + tid + 256 * j] = f2bf(a[j] - bf2f(h));
    }
}

// ---------------- Csum -> K (single bf16) + V^T (hi/lo), fused -------------
__global__ __launch_bounds__(256) void convkv_k(const float* __restrict__ Csum,
                                                u16* __restrict__ khi,
                                                u16* __restrict__ vthi,
                                                u16* __restrict__ vtlo) {
    __shared__ float vb[NCL][65];   // 66.5 KB
    const int bh = blockIdx.x;
    const int bb = bh >> 4, hh = bh & 15;
    const int tid = threadIdx.x;

    // ---- K part ----
#pragma unroll
    for (int i = 0; i < 8; ++i) {
        int ulin = tid + 256 * i;          // cl*8 + u
        int c = ulin >> 3, u = ulin & 7;
        const float* src = Csum + ((size_t)(bb * NCL + c)) * 2048 + hh * 64 + u * 8;
        float4 v0 = *(const float4*)src;
        float4 v1 = *(const float4*)(src + 4);
        size_t o = ((size_t)bh * NCL + c) * 64 + ((u ^ (c & 7)) << 3);
        ushort4 h0, h1;
        h0.x = f2bf(v0.x); h0.y = f2bf(v0.y); h0.z = f2bf(v0.z); h0.w = f2bf(v0.w);
        h1.x = f2bf(v1.x); h1.y = f2bf(v1.y); h1.z = f2bf(v1.z); h1.w = f2bf(v1.w);
        *(ushort4*)(khi + o) = h0; *(ushort4*)(khi + o + 4) = h1;
    }

    // ---- V part (transpose) ----
    const int d0 = tid & 63;
#pragma unroll
    for (int i = 0; i < 64; ++i) {
        int c = (tid >> 6) + i * 4;
        vb[c][d0] = Csum[((size_t)(bb * NCL + c)) * 2048 + 1024 + hh * 64 + d0];
    }
    __syncthreads();
    const int d = tid >> 2;
    const int uq = tid & 3;
#pragma unroll
    for (int j = 0; j < 8; ++j) {
        int u = uq * 8 + j;                // original unit (8 clusters)
        int c0 = u * 8;
        float v[8];
#pragma unroll
        for (int e = 0; e < 8; ++e) v[e] = vb[c0 + e][d];
        ushort4 h0, l0, h1, l1;
        h0.x = f2bf(v[0]); l0.x = f2bf(v[0] - bf2f(h0.x));
        h0.y = f2bf(v[1]); l0.y = f2bf(v[1] - bf2f(h0.y));
        h0.z = f2bf(v[2]); l0.z = f2bf(v[2] - bf2f(h0.z));
        h0.w = f2bf(v[3]); l0.w = f2bf(v[3] - bf2f(h0.w));
        h1.x = f2bf(v[4]); l1.x = f2bf(v[4] - bf2f(h1.x));
        h1.y = f2bf(v[5]); l1.y = f2bf(v[5] - bf2f(h1.y));
        h1.z = f2bf(v[6]); l1.z = f2bf(v[6] - bf2f(h1.z));
        h1.w = f2bf(v[7]); l1.w = f2bf(v[7] - bf2f(h1.w));
        int usw = (u & 24) | ((u ^ d) & 7);  // low3 bits XOR'd within 8-group
        size_t o = ((size_t)bh * 64 + d) * 256 + usw * 8;
        *(ushort4*)(vthi + o) = h0; *(ushort4*)(vthi + o + 4) = h1;
        *(ushort4*)(vtlo + o) = l0; *(ushort4*)(vtlo + o + 4) = l1;
    }
}

// ---------------- 128-tile split-bf16 GEMM (kept for the small Csum GEMM) --
template<int OUT>
__global__ __launch_bounds__(256) void hgemm_k(
        const u16* __restrict__ Ahi, const u16* __restrict__ Alo,
        const u16* __restrict__ Bhi, const u16* __restrict__ Blo,
        float* __restrict__ C, int ldc, const float* __restrict__ bias,
        u16* __restrict__ Ohi, u16* __restrict__ Olo) {
    __shared__ u16 sh[4][128 * 32];

    const int tid = threadIdx.x;
    const int lane = tid & 63;
    const int wid = tid >> 6;
    const int wm = wid >> 1, wn = wid & 1;
    const size_t row0 = (size_t)blockIdx.y * 128;
    const size_t col0 = (size_t)blockIdx.x * 128;

    const int sr = tid >> 2;
    const int sq = tid & 3;
    const int qs = sq ^ ((sr >> 1) & 3);

    const u16* ga0 = Ahi + (row0 + sr) * KK + qs * 8;
    const u16* ga1 = ga0 + (size_t)64 * KK;
    const u16* gA0 = Alo + (row0 + sr) * KK + qs * 8;
    const u16* gA1 = gA0 + (size_t)64 * KK;
    const u16* gb0 = Bhi + (col0 + sr) * KK + qs * 8;
    const u16* gb1 = gb0 + (size_t)64 * KK;
    const u16* gB0 = Blo + (col0 + sr) * KK + qs * 8;
    const u16* gB1 = gB0 + (size_t)64 * KK;

    u16* d = (u16*)sh + tid * 8;

    const int rA = wm * 64 + (lane & 15);
    const int rB = wn * 64 + (lane & 15);
    const int aoff = rA * 32 + (((lane >> 4) ^ ((rA >> 1) & 3)) * 8);
    const int boff = rB * 32 + (((lane >> 4) ^ ((rB >> 1) & 3)) * 8);

    f32x4 acc[4][4] = {};

    for (int k0 = 0; k0 < KK; k0 += 32) {
        gl16(ga0 + k0, d);
        gl16(ga1 + k0, d + 2048);
        gl16(gA0 + k0, d + 4096);
        gl16(gA1 + k0, d + 6144);
        gl16(gb0 + k0, d + 8192);
        gl16(gb1 + k0, d + 10240);
        gl16(gB0 + k0, d + 12288);
        gl16(gB1 + k0, d + 14336);
        __syncthreads();
        s8v ah[4], al[4], bh[4], bl[4];
#pragma unroll
        for (int i = 0; i < 4; ++i) {
            ah[i] = *(const s8v*)&sh[0][aoff + i * 512];
            al[i] = *(const s8v*)&sh[1][aoff + i * 512];
            bh[i] = *(const s8v*)&sh[2][boff + i * 512];
            bl[i] = *(const s8v*)&sh[3][boff + i * 512];
        }
#pragma unroll
        for (int i = 0; i < 4; ++i)
#pragma unroll
            for (int j = 0; j < 4; ++j) {
                acc[i][j] = __builtin_amdgcn_mfma_f32_16x16x32_bf16(ah[i], bh[j], acc[i][j], 0, 0, 0);
                acc[i][j] = __builtin_amdgcn_mfma_f32_16x16x32_bf16(ah[i], bl[j], acc[i][j], 0, 0, 0);
                acc[i][j] = __builtin_amdgcn_mfma_f32_16x16x32_bf16(al[i], bh[j], acc[i][j], 0, 0, 0);
            }
        __syncthreads();
    }

    const int fr = (lane >> 4) * 4;
    const int fc = lane & 15;

    float bj[4] = {0.f, 0.f, 0.f, 0.f};
    if constexpr (OUT == 1) {
#pragma unroll
        for (int j = 0; j < 4; ++j) bj[j] = bias[col0 + wn * 64 + j * 16 + fc];
    }
#pragma unroll
    for (int i = 0; i < 4; ++i)
#pragma unroll
        for (int j = 0; j < 4; ++j) {
            size_t rbase = row0 + wm * 64 + i * 16 + fr;
            size_t cidx = col0 + wn * 64 + j * 16 + fc;
#pragma unroll
            for (int g = 0; g < 4; ++g)
                C[(rbase + g) * (size_t)ldc + cidx] = acc[i][j][g] + bj[j];
        }
}

// ---------------- 256-tile 8-wave phased split-bf16 GEMM -------------------
// OUT=1/SGL=0: R13 4-phase schedule (heavy hi/lo out-proj path).
// SGL=1 (score path, single bf16): barrier-light loop (R18).
template<int OUT, int SGL>
__global__ __launch_bounds__(512) void hgemm256_k(
        const u16* __restrict__ Ahi, const u16* __restrict__ Alo,
        const u16* __restrict__ Bhi, const u16* __restrict__ Blo,
        float* __restrict__ C, int ldc, const float* __restrict__ bias,
        u16* __restrict__ Ohi, u16* __restrict__ Olo) {
    __shared__ u16 sh[2][4][8192];   // [buf][Ahi|Alo|Bhi|Blo][256*32]

    const int tid = threadIdx.x;
    const int lane = tid & 63;
    const int wid = tid >> 6;
    const int wm = wid >> 2, wn = wid & 3;
    const int l15 = lane & 15;

    const int nwg = gridDim.x;
    const int cpx = nwg >> 3;
    const int lin = blockIdx.x;
    const int swz = (lin & 7) * cpx + (lin >> 3);
    const int bx = swz & 3;          // N = 1024 -> 4 col tiles
    const int by = swz >> 2;

    const size_t row0 = (size_t)by * 256;
    const size_t col0 = (size_t)bx * 256;

    const int sr0 = tid >> 2;            // 0..127
    const int qs0 = (tid & 3) ^ ((sr0 >> 1) & 3);
    const u16* pAh0 = Ahi + (row0 + sr0) * KK + qs0 * 8;
    const u16* pAh1 = pAh0 + (size_t)128 * KK;
    const u16* pAl0 = Alo + (row0 + sr0) * KK + qs0 * 8;
    const u16* pAl1 = pAl0 + (size_t)128 * KK;
    const u16* pBh0 = Bhi + (col0 + sr0) * KK + qs0 * 8;
    const u16* pBh1 = pBh0 + (size_t)128 * KK;
    const u16* pBl0 = Blo + (col0 + sr0) * KK + qs0 * 8;
    const u16* pBl1 = pBl0 + (size_t)128 * KK;

#define STG_A(bw, k) { u16* db = (u16*)sh + (bw) * 32768 + tid * 8;            \
        gl16(pAh0 + (k), db);            gl16(pAh1 + (k), db + 4096);          \
        if constexpr (!SGL) {                                                  \
            gl16(pAl0 + (k), db + 8192); gl16(pAl1 + (k), db + 12288); } }
#define STG_B(bw, k) { u16* db = (u16*)sh + (bw) * 32768 + 16384 + tid * 8;    \
        gl16(pBh0 + (k), db);            gl16(pBh1 + (k), db + 4096);          \
        if constexpr (!SGL) {                                                  \
            gl16(pBl0 + (k), db + 8192); gl16(pBl1 + (k), db + 12288); } }

    const int rA = wm * 128 + l15;
    const int rB = wn * 64 + l15;
    const int aoff = rA * 32 + (((lane >> 4) ^ ((rA >> 1) & 3)) * 8);
    const int boff = rB * 32 + (((lane >> 4) ^ ((rB >> 1) & 3)) * 8);

    f32x4 acc[8][4] = {};

    STG_A(0, 0);
    STG_B(0, 0);
    __syncthreads();

    int cur = 0;
    for (int kt = 0; kt < 32; ++kt) {
        const int kn = (kt + 1) * 32;
        const u16* br = (const u16*)sh + cur * 32768;
        const int bw = cur ^ 1;
        const bool st = kt < 31;

        if constexpr (SGL) {
            // ---- barrier-light: stage t+1, read all frags, 32 MFMA ----
            if (st) { STG_A(bw, kn); STG_B(bw, kn); }
            s8v bhf[4];
#pragma unroll
            for (int ni = 0; ni < 4; ++ni)
                bhf[ni] = *(const s8v*)(br + 16384 + boff + ni * 512);
            s8v ahf[8];
#pragma unroll
            for (int mi = 0; mi < 8; ++mi)
                ahf[mi] = *(const s8v*)(br + aoff + mi * 512);
            __builtin_amdgcn_s_setprio(1);
#pragma unroll
            for (int mi = 0; mi < 8; ++mi)
#pragma unroll
                for (int ni = 0; ni < 4; ++ni)
                    acc[mi][ni] = __builtin_amdgcn_mfma_f32_16x16x32_bf16(ahf[mi], bhf[ni], acc[mi][ni], 0, 0, 0);
            __builtin_amdgcn_s_setprio(0);
            __syncthreads();
            cur ^= 1;
            continue;
        }

        // ---- hi/lo path: R13 4-phase schedule (unchanged) ----
        if (st) STG_A(bw, kn);
        s8v bhf[4], blf[4];
#pragma unroll
        for (int ni = 0; ni < 4; ++ni) {
            bhf[ni] = *(const s8v*)(br + 16384 + boff + ni * 512);
            blf[ni] = *(const s8v*)(br + 24576 + boff + ni * 512);
        }
        {
            s8v ah0 = *(const s8v*)(br + aoff);
            s8v al0 = *(const s8v*)(br + 8192 + aoff);
            s8v ah1 = *(const s8v*)(br + aoff + 512);
            s8v al1 = *(const s8v*)(br + 8192 + aoff + 512);
            __builtin_amdgcn_s_setprio(1);
#pragma unroll
            for (int ni = 0; ni < 4; ++ni) {
                acc[0][ni] = __builtin_amdgcn_mfma_f32_16x16x32_bf16(ah0, bhf[ni], acc[0][ni], 0, 0, 0);
                acc[0][ni] = __builtin_amdgcn_mfma_f32_16x16x32_bf16(ah0, blf[ni], acc[0][ni], 0, 0, 0);
                acc[0][ni] = __builtin_amdgcn_mfma_f32_16x16x32_bf16(al0, bhf[ni], acc[0][ni], 0, 0, 0);
                acc[1][ni] = __builtin_amdgcn_mfma_f32_16x16x32_bf16(ah1, bhf[ni], acc[1][ni], 0, 0, 0);
                acc[1][ni] = __builtin_amdgcn_mfma_f32_16x16x32_bf16(ah1, blf[ni], acc[1][ni], 0, 0, 0);
                acc[1][ni] = __builtin_amdgcn_mfma_f32_16x16x32_bf16(al1, bhf[ni], acc[1][ni], 0, 0, 0);
            }
            __builtin_amdgcn_s_setprio(0);
        }
        __builtin_amdgcn_s_barrier();

#pragma unroll
        for (int p = 1; p < 4; ++p) {
            if (p == 1 && st) STG_B(bw, kn);
            const int m0 = 2 * p;
            s8v ah0 = *(const s8v*)(br + aoff + m0 * 512);
            s8v al0 = *(const s8v*)(br + 8192 + aoff + m0 * 512);
            s8v ah1 = *(const s8v*)(br + aoff + (m0 + 1) * 512);
            s8v al1 = *(const s8v*)(br + 8192 + aoff + (m0 + 1) * 512);
            __builtin_amdgcn_s_setprio(1);
#pragma unroll
            for (int ni = 0; ni < 4; ++ni) {
                acc[m0][ni] = __builtin_amdgcn_mfma_f32_16x16x32_bf16(ah0, bhf[ni], acc[m0][ni], 0, 0, 0);
                acc[m0][ni] = __builtin_amdgcn_mfma_f32_16x16x32_bf16(ah0, blf[ni], acc[m0][ni], 0, 0, 0);
                acc[m0][ni] = __builtin_amdgcn_mfma_f32_16x16x32_bf16(al0, bhf[ni], acc[m0][ni], 0, 0, 0);
                acc[m0 + 1][ni] = __builtin_amdgcn_mfma_f32_16x16x32_bf16(ah1, bhf[ni], acc[m0 + 1][ni], 0, 0, 0);
                acc[m0 + 1][ni] = __builtin_amdgcn_mfma_f32_16x16x32_bf16(ah1, blf[ni], acc[m0 + 1][ni], 0, 0, 0);
                acc[m0 + 1][ni] = __builtin_amdgcn_mfma_f32_16x16x32_bf16(al1, bhf[ni], acc[m0 + 1][ni], 0, 0, 0);
            }
            __builtin_amdgcn_s_setprio(0);
            if (p < 3) __builtin_amdgcn_s_barrier();
        }

        __syncthreads();
        cur ^= 1;
    }
#undef STG_A
#undef STG_B

    const int fr = (lane >> 4) * 4;
    const int fc = lane & 15;

    if constexpr (OUT == 2) {
#pragma unroll
        for (int mi = 0; mi < 8; ++mi)
#pragma unroll
            for (int ni = 0; ni < 4; ++ni) {
                size_t rbase = row0 + wm * 128 + mi * 16 + fr;
                size_t cidx = col0 + wn * 64 + ni * 16 + fc;
#pragma unroll
                for (int g = 0; g < 4; ++g) {
                    float o = acc[mi][ni][g];
                    u16 h = f2bf(o);
                    size_t idx = (rbase + g) * 1024 + cidx;
                    Ohi[idx] = h;
                    if constexpr (!SGL) {
                        Olo[idx] = f2bf(o - bf2f(h));
                    }
                }
            }
    } else {
        float bj[4];
#pragma unroll
        for (int ni = 0; ni < 4; ++ni) bj[ni] = bias[col0 + wn * 64 + ni * 16 + fc];
#pragma unroll
        for (int mi = 0; mi < 8; ++mi)
#pragma unroll
            for (int ni = 0; ni < 4; ++ni) {
                size_t rbase = row0 + wm * 128 + mi * 16 + fr;
                size_t cidx = col0 + wn * 64 + ni * 16 + fc;
#pragma unroll
                for (int g = 0; g < 4; ++g)
                    C[(rbase + g) * (size_t)ldc + cidx] = acc[mi][ni][g] + bj[ni];
            }
    }
}

// ---------------- fused MFMA attention (R17, unchanged) --------------------
__global__ __launch_bounds__(256) void fattn_k(const u16* __restrict__ Qhi,
                                               const u16* __restrict__ Khi,
                                               const u16* __restrict__ Vthi,
                                               const u16* __restrict__ Vtlo,
                                               const float2* __restrict__ tab,
                                               u16* __restrict__ Phi,
                                               u16* __restrict__ Plo) {
    __shared__ u16 qh[64 * 64];      // 8 KB  [tok][unit^(tok&7) * 8]
    __shared__ u16 zb[16 * 512];     // 16 KB [(w*4+cf)*512 + lane*8 + e]
    __shared__ float lpart[4][64];
    __shared__ float invl[64];

    const int tid = threadIdx.x;
    const int lane = tid & 63;
    const int w = tid >> 6;
    const int g = lane >> 4;
    const int l15 = lane & 15;
    const int hh = blockIdx.y, bb = blockIdx.z;
    const int bh = bb * 16 + hh;
    const int tok0 = blockIdx.x * 64;

    // ---- stage Q into LDS (source pre-swizzled; dest linear) ----
#pragma unroll
    for (int i = 0; i < 2; ++i) {
        int ulin = tid + 256 * i;          // tok*8 + u'
        int tok = ulin >> 3, up = ulin & 7;
        size_t src = ((size_t)(bb * NN + tok0 + tok)) * 1024 + hh * 64
                     + ((up ^ (tok & 7)) << 3);
        gl16(Qhi + src, qh + ulin * 8);
    }
    __syncthreads();

    const size_t kbase = (size_t)bh * NCL * 64;
    const size_t vbase = (size_t)bh * 64 * 256;
    const int dg = w * 16 + l15;

    float lp[4] = {0.f, 0.f, 0.f, 0.f};
    f32x4 oacc[4] = {};

#pragma unroll
    for (int h = 0; h < 2; ++h) {
        // ---- QK^T for f in {2h, 2h+1} (single-bf16 both operands) ----
        f32x4 acch[2][4] = {};
#pragma unroll
        for (int ff = 0; ff < 2; ++ff) {
            const int f = 2 * h + ff;
            const int cl = w * 64 + f * 16 + l15;
            s8v kf[2];
#pragma unroll
            for (int ks = 0; ks < 2; ++ks) {
                size_t ko = kbase + (size_t)cl * 64 + (((ks * 4 + g) ^ (l15 & 7)) << 3);
                kf[ks] = *(const s8v*)(Khi + ko);
            }
#pragma unroll
            for (int cf = 0; cf < 4; ++cf) {
                const int qr = cf * 16 + l15;   // token row in LDS
#pragma unroll
                for (int ks = 0; ks < 2; ++ks) {
                    int qa = qr * 64 + (((ks * 4 + g) ^ (qr & 7)) << 3);
                    s8v qfh = *(const s8v*)&qh[qa];
                    acch[ff][cf] = __builtin_amdgcn_mfma_f32_16x16x32_bf16(kf[ks], qfh, acch[ff][cf], 0, 0, 0);
                }
            }
        }

        // ---- softmax weights -> read-linear z (single RNE bf16) ----
#pragma unroll
        for (int ff = 0; ff < 2; ++ff) {
            const int f = 2 * h + ff;
            float2 t4[4];
#pragma unroll
            for (int r = 0; r < 4; ++r)
                t4[r] = tab[bb * NCL + w * 64 + f * 16 + 4 * g + r];
#pragma unroll
            for (int cf = 0; cf < 4; ++cf) {
                float z[4];
#pragma unroll
                for (int r = 0; r < 4; ++r) {
                    float e = __expf(acch[ff][cf][r] * t4[r].x);
                    lp[cf] += t4[r].y * e;
                    z[r] = t4[r].y > 0.f ? e : 0.f;
                }
                uint2 pz;
                pz.x = (unsigned int)f2bf(z[0]) | ((unsigned int)f2bf(z[1]) << 16);
                pz.y = (unsigned int)f2bf(z[2]) | ((unsigned int)f2bf(z[3]) << 16);
                int a16 = (w * 4 + cf) * 512
                          + ((2 * ff + (g >> 1)) * 16 + l15) * 8 + 4 * (g & 1);
                *(uint2*)&zb[a16] = pz;
            }
        }

        if (h == 1) {
#pragma unroll
            for (int cf = 0; cf < 4; ++cf) {
                float v = lp[cf];
                v += __shfl_xor(v, 16);
                v += __shfl_xor(v, 32);
                lp[cf] = v;
            }
            if (lane < 16) {
#pragma unroll
                for (int cf = 0; cf < 4; ++cf) lpart[w][cf * 16 + lane] = lp[cf];
            }
        }
        __syncthreads();   // z half ready (h=1: + lpart ready)

        if (h == 1 && w == 0)
            invl[lane] = 1.f / (lpart[0][lane] + lpart[1][lane] + lpart[2][lane] + lpart[3][lane]);

        // ---- PV for this half: ks = 2s+h, z chunk = s*4+cf (2 MFMA) ----
#pragma unroll
        for (int s = 0; s < 4; ++s) {
            int kst = 2 * s + h;
            size_t vo = vbase + (size_t)dg * 256
                        + (((kst * 4 + g) & 24) | (((kst * 4 + g) ^ dg) & 7)) * 8;
            s8v vh = *(const s8v*)(Vthi + vo);
            s8v vl = *(const s8v*)(Vtlo + vo);
#pragma unroll
            for (int cf = 0; cf < 4; ++cf) {
                int a16 = (s * 4 + cf) * 512 + lane * 8;
                s8v zf = *(const s8v*)&zb[a16];
                oacc[cf] = __builtin_amdgcn_mfma_f32_16x16x32_bf16(vh, zf, oacc[cf], 0, 0, 0);
                oacc[cf] = __builtin_amdgcn_mfma_f32_16x16x32_bf16(vl, zf, oacc[cf], 0, 0, 0);
            }
        }
        __syncthreads();   // z reads done (h=0) / invl ready (h=1)
    }

    // ---- epilogue: scale by 1/l, trunc hi/lo pack, store ----
#pragma unroll
    for (int cf = 0; cf < 4; ++cf) {
        const int tokL = cf * 16 + l15;
        float il = invl[tokL];
        float o0 = oacc[cf][0] * il, o1 = oacc[cf][1] * il;
        float o2 = oacc[cf][2] * il, o3 = oacc[cf][3] * il;
        unsigned int b0 = __float_as_uint(o0), b1 = __float_as_uint(o1);
        unsigned int b2 = __float_as_uint(o2), b3 = __float_as_uint(o3);
        float r0 = o0 - __uint_as_float(b0 & 0xFFFF0000u);
        float r1 = o1 - __uint_as_float(b1 & 0xFFFF0000u);
        float r2 = o2 - __uint_as_float(b2 & 0xFFFF0000u);
        float r3 = o3 - __uint_as_float(b3 & 0xFFFF0000u);
        uint2 ph, pl;
        ph.x = pk2hi(b0, b1); ph.y = pk2hi(b2, b3);
        pl.x = pk2hi(__float_as_uint(r0), __float_as_uint(r1));
        pl.y = pk2hi(__float_as_uint(r2), __float_as_uint(r3));
        size_t po = ((size_t)(bb * NN + tok0 + tokL)) * 1024 + hh * 64 + w * 16 + 4 * g;
        *(uint2*)(Phi + po) = ph;
        *(uint2*)(Plo + po) = pl;
    }
}

// ---------------- launcher -------------------------------------------------
extern "C" void kernel_launch(void* const* d_in, const int* in_sizes, int n_in,
                              void* d_out, int out_size, void* d_ws, size_t ws_size,
                              hipStream_t stream) {
    const int* cluster  = (const int*)d_in[0];
    const float* x      = (const float*)d_in[1];
    const float* w_q    = (const float*)d_in[2];
    const float* w_kv   = (const float*)d_in[3];
    const float* w_proj = (const float*)d_in[4];
    const float* b_proj = (const float*)d_in[5];
    float* out = (float*)d_out;

    // layout (~312 MiB)
    const size_t SZ_H  = (size_t)MM * 1024 * 2;      // 64 MiB
    const size_t SZ_W  = (size_t)4096 * 1024 * 2;    // 8 MiB
    const size_t SZ_XS = (size_t)2048 * 1024 * 2;    // 4 MiB
    const size_t SZ_CS = (size_t)2048 * 2048 * 4;    // 16 MiB
    const size_t SZ_KV = (size_t)128 * NCL * 64 * 2; // 4 MiB

    char* p = (char*)d_ws;
    u16* Xhi = (u16*)p;   p += SZ_H;    // Phi (fattn out / out-proj A hi)
    u16* Xlo = (u16*)p;   p += SZ_H;    // Plo
    u16* Qhi = (u16*)p;   p += SZ_H;
    u16* Qlo = (u16*)p;   p += SZ_H;    // unused (layout stability)
    u16* Wthi = (u16*)p;  p += SZ_W;
    u16* Wtlo = (u16*)p;  p += SZ_W;
    u16* XShi = (u16*)p;  p += SZ_XS;
    u16* XSlo = (u16*)p;  p += SZ_XS;
    float* Csum = (float*)p; p += SZ_CS;
    u16* Khi = (u16*)p;   p += SZ_KV;
    u16* Klo = (u16*)p;   p += SZ_KV;   // unused
    u16* Vthi = (u16*)p;  p += SZ_KV;
    u16* Vtlo = (u16*)p;  p += SZ_KV;
    float2* tab = (float2*)p; p += 2048 * sizeof(float2);
    int* counts = (int*)p;   p += 2048 * sizeof(int);
    int* tokidx = (int*)p;   p += (size_t)BB * NN * sizeof(int);
    int* starts = (int*)p;
    (void)Klo; (void)Qlo;

    // fused prep: counts + tab + stable counting sort
    prep_k<<<BB, 256, 0, stream>>>(cluster, counts, tab, tokidx, starts);

    convx1_k<<<(size_t)MM * KK / 1024, 256, 0, stream>>>(x, Xhi);
    convw3_k<<<dim3(64, 32, 3), 256, 0, stream>>>(w_q, w_kv, w_proj, Wthi, Wtlo);

    xsum2_k<<<BB * NCL, 256, 0, stream>>>(x, tokidx, starts, counts, XShi, XSlo);

    // Q = X @ Wq^T (single-bf16 score path, barrier-light) -> Qhi
    hgemm256_k<2, 1><<<512, 512, 0, stream>>>(Xhi, Xlo, Wthi, Wtlo,
                                              nullptr, 0, nullptr, Qhi, Qlo);
    // Csum = XS @ Wkv^T (ksum | vsum), fp32 (full hi/lo: V path)
    hgemm_k<0><<<dim3(16, 16), 256, 0, stream>>>(XShi, XSlo,
                                                 Wthi + (size_t)1024 * KK, Wtlo + (size_t)1024 * KK,
                                                 Csum, 2048, nullptr, nullptr, nullptr);
    // K (single bf16) + V^T (hi/lo), fused conversion
    convkv_k<<<128, 256, 0, stream>>>(Csum, Khi, Vthi, Vtlo);

    // fused attention -> P (bf16 hi/lo, aliases X buffers); 64-tok blocks
    fattn_k<<<dim3(NN / 64, HEADS, BB), 256, 0, stream>>>(Qhi, Khi,
                                                          Vthi, Vtlo, tab, Xhi, Xlo);
    // out = P @ Wproj^T + bias (full hi/lo: R13 4-phase schedule)
    hgemm256_k<1, 0><<<512, 512, 0, stream>>>(Xhi, Xlo,
                                              Wthi + (size_t)3072 * KK, Wtlo + (size_t)3072 * KK,
                                              out, 1024, b_proj, nullptr, nullptr);
}

// Round 21
// 554.671 us; speedup vs baseline: 1.0741x; 1.0478x over previous
//
#include <hip/hip_runtime.h>
#include <hip/hip_bf16.h>
#include <math.h>

#define HEADS 16
#define NCL 256
#define BB 8
#define NN 4096
#define DD 1024
#define DH 64
#define MM (BB*NN)   // 32768
#define KK 1024

typedef unsigned short u16;
typedef __attribute__((ext_vector_type(8))) short s8v;     // 8 bf16 (4 VGPRs)
typedef __attribute__((ext_vector_type(4))) float f32x4;   // MFMA C/D

__device__ __forceinline__ float bf2f(u16 u) {
    union { unsigned int i; float f; } v; v.i = ((unsigned int)u) << 16; return v.f;
}
__device__ __forceinline__ u16 f2bf(float x) {   // round-to-nearest-even
    union { float f; unsigned int i; } v; v.f = x;
    unsigned int u = v.i;
    return (u16)((u + 0x7FFFu + ((u >> 16) & 1u)) >> 16);
}
// pack hi16 halves of two f32 bit-patterns: low16 = a.hi16, high16 = b.hi16
__device__ __forceinline__ unsigned int pk2hi(unsigned int a, unsigned int b) {
    return __builtin_amdgcn_perm(b, a, 0x07060302);
}
__device__ __forceinline__ void gl16(const u16* g, u16* l) {
    __builtin_amdgcn_global_load_lds(
        (__attribute__((address_space(1))) void*)g,
        (__attribute__((address_space(3))) void*)l, 16, 0, 0);
}

// ---------------- fused prologue: prep | convw3 | convx1 (block-special) ----
// All three are mutually independent; merging lets the tiny prep (8 blocks)
// and convw3 (6144 blocks) run concurrently under convx1's (32768 blocks)
// memory-bound shadow instead of serializing as 3 launches.
// blocks [0,8): prep; [8,6152): convw3; [6152,38920): convx1.
__global__ __launch_bounds__(256) void prologue_k(
        const int* __restrict__ cluster, int* __restrict__ counts,
        float2* __restrict__ tab, int* __restrict__ tokidx,
        int* __restrict__ starts,
        const float* __restrict__ x, u16* __restrict__ xhi,
        const float* __restrict__ wq, const float* __restrict__ wkv,
        const float* __restrict__ wproj,
        u16* __restrict__ thi, u16* __restrict__ tlo) {
    __shared__ int cl[NN];    // 16 KB (prep); reused as float[32][33] (convw)
    __shared__ int pf[NCL];
    const int bid = blockIdx.x;
    const int tid = threadIdx.x;

    if (bid < 8) {
        // ================= prep: counts + tab + stable counting sort =======
        const int bb = bid;
        pf[tid] = 0;
        __syncthreads();
        for (int i = tid; i < NN; i += 256) {
            int c = cluster[bb * NN + i];
            cl[i] = c;
            atomicAdd(&pf[c], 1);
        }
        __syncthreads();

        const int myc = pf[tid];
        counts[bb * NCL + tid] = myc;
        float2 t;
        t.x = myc > 0 ? 0.125f / (float)myc : 0.f;
        t.y = (float)myc;
        tab[bb * NCL + tid] = t;

        for (int off = 1; off < NCL; off <<= 1) {
            int v = (tid >= off) ? pf[tid - off] : 0;
            __syncthreads();
            pf[tid] += v;
            __syncthreads();
        }
        int start = pf[tid] - myc;   // exclusive prefix
        starts[bb * NCL + tid] = start;

        int* dst = tokidx + bb * NN + start;
        int rank = 0;
        for (int t0 = 0; t0 < NN; t0 += 16) {
            int c16[16];
#pragma unroll
            for (int j = 0; j < 16; ++j) c16[j] = cl[t0 + j];   // batched
#pragma unroll
            for (int j = 0; j < 16; ++j) {
                if (c16[j] == tid) { dst[rank] = t0 + j; ++rank; }
            }
        }
    } else if (bid < 8 + 6144) {
        // ================= convw3: [K][N] fp32 -> [N][K] bf16 hi/lo ========
        float (*tt)[33] = (float (*)[33])cl;   // 4.2 KB, reuses prep LDS
        const int lin = bid - 8;
        const int wz = lin >> 11;              // 2048 blocks per weight
        const int r = lin & 2047;
        const int bx = r & 63, by = r >> 6;
        const int N = (wz == 1) ? 2048 : 1024;
        if (bx * 32 >= N) return;
        const float* w = (wz == 0) ? wq : (wz == 1) ? wkv : wproj;
        const size_t nbase = (wz == 0) ? 0 : (wz == 1) ? 1024 : 3072;
        const int lx = tid & 31, ly = tid >> 5;   // ly 0..7
#pragma unroll
        for (int p = 0; p < 4; ++p)
            tt[p * 8 + ly][lx] = w[(size_t)(by * 32 + p * 8 + ly) * N + bx * 32 + lx];
        __syncthreads();
#pragma unroll
        for (int p = 0; p < 4; ++p) {
            size_t n = nbase + bx * 32 + p * 8 + ly;
            int k = by * 32 + lx;
            float v = tt[lx][p * 8 + ly];
            u16 h = f2bf(v);
            thi[n * KK + k] = h;
            tlo[n * KK + k] = f2bf(v - bf2f(h));
        }
    } else {
        // ================= convx1: x -> single bf16 (score path) ===========
        size_t i = ((size_t)(bid - 6152) * 256 + tid) * 4;
        float4 v = *(const float4*)(x + i);
        ushort4 h;
        h.x = f2bf(v.x); h.y = f2bf(v.y); h.z = f2bf(v.z); h.w = f2bf(v.w);
        *(ushort4*)(xhi + i) = h;
    }
}

// ---------------- segment-sum of x via sorted index list (V path: hi/lo) ---
__global__ __launch_bounds__(256) void xsum2_k(const float* __restrict__ x,
                                               const int* __restrict__ tokidx,
                                               const int* __restrict__ starts,
                                               const int* __restrict__ counts,
                                               u16* __restrict__ shi,
                                               u16* __restrict__ slo) {
    const int bb = blockIdx.x >> 8;
    const int c = blockIdx.x & (NCL - 1);
    const int tid = threadIdx.x;
    const int start = starts[bb * NCL + c];
    const int cnt = counts[bb * NCL + c];
    const int* ti = tokidx + bb * NN + start;

    float a[4] = {0.f, 0.f, 0.f, 0.f};
    for (int i = 0; i < cnt; ++i) {
        int t = ti[i];
        const float* xr = x + ((size_t)bb * NN + t) * DD;
#pragma unroll
        for (int j = 0; j < 4; ++j) a[j] += xr[tid + 256 * j];
    }
    size_t o = ((size_t)bb * NCL + c) * DD;
#pragma unroll
    for (int j = 0; j < 4; ++j) {
        u16 h = f2bf(a[j]);
        shi[o + tid + 256 * j] = h;
        slo[o + tid + 256 * j] = f2bf(a[j] - bf2f(h));
    }
}

// ---------------- Csum -> K (single bf16) + V^T (hi/lo), fused -------------
__global__ __launch_bounds__(256) void convkv_k(const float* __restrict__ Csum,
                                                u16* __restrict__ khi,
                                                u16* __restrict__ vthi,
                                                u16* __restrict__ vtlo) {
    __shared__ float vb[NCL][65];   // 66.5 KB
    const int bh = blockIdx.x;
    const int bb = bh >> 4, hh = bh & 15;
    const int tid = threadIdx.x;

    // ---- K part ----
#pragma unroll
    for (int i = 0; i < 8; ++i) {
        int ulin = tid + 256 * i;          // cl*8 + u
        int c = ulin >> 3, u = ulin & 7;
        const float* src = Csum + ((size_t)(bb * NCL + c)) * 2048 + hh * 64 + u * 8;
        float4 v0 = *(const float4*)src;
        float4 v1 = *(const float4*)(src + 4);
        size_t o = ((size_t)bh * NCL + c) * 64 + ((u ^ (c & 7)) << 3);
        ushort4 h0, h1;
        h0.x = f2bf(v0.x); h0.y = f2bf(v0.y); h0.z = f2bf(v0.z); h0.w = f2bf(v0.w);
        h1.x = f2bf(v1.x); h1.y = f2bf(v1.y); h1.z = f2bf(v1.z); h1.w = f2bf(v1.w);
        *(ushort4*)(khi + o) = h0; *(ushort4*)(khi + o + 4) = h1;
    }

    // ---- V part (transpose) ----
    const int d0 = tid & 63;
#pragma unroll
    for (int i = 0; i < 64; ++i) {
        int c = (tid >> 6) + i * 4;
        vb[c][d0] = Csum[((size_t)(bb * NCL + c)) * 2048 + 1024 + hh * 64 + d0];
    }
    __syncthreads();
    const int d = tid >> 2;
    const int uq = tid & 3;
#pragma unroll
    for (int j = 0; j < 8; ++j) {
        int u = uq * 8 + j;                // original unit (8 clusters)
        int c0 = u * 8;
        float v[8];
#pragma unroll
        for (int e = 0; e < 8; ++e) v[e] = vb[c0 + e][d];
        ushort4 h0, l0, h1, l1;
        h0.x = f2bf(v[0]); l0.x = f2bf(v[0] - bf2f(h0.x));
        h0.y = f2bf(v[1]); l0.y = f2bf(v[1] - bf2f(h0.y));
        h0.z = f2bf(v[2]); l0.z = f2bf(v[2] - bf2f(h0.z));
        h0.w = f2bf(v[3]); l0.w = f2bf(v[3] - bf2f(h0.w));
        h1.x = f2bf(v[4]); l1.x = f2bf(v[4] - bf2f(h1.x));
        h1.y = f2bf(v[5]); l1.y = f2bf(v[5] - bf2f(h1.y));
        h1.z = f2bf(v[6]); l1.z = f2bf(v[6] - bf2f(h1.z));
        h1.w = f2bf(v[7]); l1.w = f2bf(v[7] - bf2f(h1.w));
        int usw = (u & 24) | ((u ^ d) & 7);  // low3 bits XOR'd within 8-group
        size_t o = ((size_t)bh * 64 + d) * 256 + usw * 8;
        *(ushort4*)(vthi + o) = h0; *(ushort4*)(vthi + o + 4) = h1;
        *(ushort4*)(vtlo + o) = l0; *(ushort4*)(vtlo + o + 4) = l1;
    }
}

// ---------------- 128-tile split-bf16 GEMM (kept for the small Csum GEMM) --
template<int OUT>
__global__ __launch_bounds__(256) void hgemm_k(
        const u16* __restrict__ Ahi, const u16* __restrict__ Alo,
        const u16* __restrict__ Bhi, const u16* __restrict__ Blo,
        float* __restrict__ C, int ldc, const float* __restrict__ bias,
        u16* __restrict__ Ohi, u16* __restrict__ Olo) {
    __shared__ u16 sh[4][128 * 32];

    const int tid = threadIdx.x;
    const int lane = tid & 63;
    const int wid = tid >> 6;
    const int wm = wid >> 1, wn = wid & 1;
    const size_t row0 = (size_t)blockIdx.y * 128;
    const size_t col0 = (size_t)blockIdx.x * 128;

    const int sr = tid >> 2;
    const int sq = tid & 3;
    const int qs = sq ^ ((sr >> 1) & 3);

    const u16* ga0 = Ahi + (row0 + sr) * KK + qs * 8;
    const u16* ga1 = ga0 + (size_t)64 * KK;
    const u16* gA0 = Alo + (row0 + sr) * KK + qs * 8;
    const u16* gA1 = gA0 + (size_t)64 * KK;
    const u16* gb0 = Bhi + (col0 + sr) * KK + qs * 8;
    const u16* gb1 = gb0 + (size_t)64 * KK;
    const u16* gB0 = Blo + (col0 + sr) * KK + qs * 8;
    const u16* gB1 = gB0 + (size_t)64 * KK;

    u16* d = (u16*)sh + tid * 8;

    const int rA = wm * 64 + (lane & 15);
    const int rB = wn * 64 + (lane & 15);
    const int aoff = rA * 32 + (((lane >> 4) ^ ((rA >> 1) & 3)) * 8);
    const int boff = rB * 32 + (((lane >> 4) ^ ((rB >> 1) & 3)) * 8);

    f32x4 acc[4][4] = {};

    for (int k0 = 0; k0 < KK; k0 += 32) {
        gl16(ga0 + k0, d);
        gl16(ga1 + k0, d + 2048);
        gl16(gA0 + k0, d + 4096);
        gl16(gA1 + k0, d + 6144);
        gl16(gb0 + k0, d + 8192);
        gl16(gb1 + k0, d + 10240);
        gl16(gB0 + k0, d + 12288);
        gl16(gB1 + k0, d + 14336);
        __syncthreads();
        s8v ah[4], al[4], bh[4], bl[4];
#pragma unroll
        for (int i = 0; i < 4; ++i) {
            ah[i] = *(const s8v*)&sh[0][aoff + i * 512];
            al[i] = *(const s8v*)&sh[1][aoff + i * 512];
            bh[i] = *(const s8v*)&sh[2][boff + i * 512];
            bl[i] = *(const s8v*)&sh[3][boff + i * 512];
        }
#pragma unroll
        for (int i = 0; i < 4; ++i)
#pragma unroll
            for (int j = 0; j < 4; ++j) {
                acc[i][j] = __builtin_amdgcn_mfma_f32_16x16x32_bf16(ah[i], bh[j], acc[i][j], 0, 0, 0);
                acc[i][j] = __builtin_amdgcn_mfma_f32_16x16x32_bf16(ah[i], bl[j], acc[i][j], 0, 0, 0);
                acc[i][j] = __builtin_amdgcn_mfma_f32_16x16x32_bf16(al[i], bh[j], acc[i][j], 0, 0, 0);
            }
        __syncthreads();
    }

    const int fr = (lane >> 4) * 4;
    const int fc = lane & 15;

    float bj[4] = {0.f, 0.f, 0.f, 0.f};
    if constexpr (OUT == 1) {
#pragma unroll
        for (int j = 0; j < 4; ++j) bj[j] = bias[col0 + wn * 64 + j * 16 + fc];
    }
#pragma unroll
    for (int i = 0; i < 4; ++i)
#pragma unroll
        for (int j = 0; j < 4; ++j) {
            size_t rbase = row0 + wm * 64 + i * 16 + fr;
            size_t cidx = col0 + wn * 64 + j * 16 + fc;
#pragma unroll
            for (int g = 0; g < 4; ++g)
                C[(rbase + g) * (size_t)ldc + cidx] = acc[i][j][g] + bj[j];
        }
}

// ---------------- 256-tile 8-wave phased split-bf16 GEMM -------------------
// OUT=1/SGL=0: R13 4-phase schedule (heavy hi/lo out-proj path).
// SGL=1 (score path, single bf16): barrier-light loop (R18).
template<int OUT, int SGL>
__global__ __launch_bounds__(512) void hgemm256_k(
        const u16* __restrict__ Ahi, const u16* __restrict__ Alo,
        const u16* __restrict__ Bhi, const u16* __restrict__ Blo,
        float* __restrict__ C, int ldc, const float* __restrict__ bias,
        u16* __restrict__ Ohi, u16* __restrict__ Olo) {
    __shared__ u16 sh[2][4][8192];   // [buf][Ahi|Alo|Bhi|Blo][256*32]

    const int tid = threadIdx.x;
    const int lane = tid & 63;
    const int wid = tid >> 6;
    const int wm = wid >> 2, wn = wid & 3;
    const int l15 = lane & 15;

    const int nwg = gridDim.x;
    const int cpx = nwg >> 3;
    const int lin = blockIdx.x;
    const int swz = (lin & 7) * cpx + (lin >> 3);
    const int bx = swz & 3;          // N = 1024 -> 4 col tiles
    const int by = swz >> 2;

    const size_t row0 = (size_t)by * 256;
    const size_t col0 = (size_t)bx * 256;

    const int sr0 = tid >> 2;            // 0..127
    const int qs0 = (tid & 3) ^ ((sr0 >> 1) & 3);
    const u16* pAh0 = Ahi + (row0 + sr0) * KK + qs0 * 8;
    const u16* pAh1 = pAh0 + (size_t)128 * KK;
    const u16* pAl0 = Alo + (row0 + sr0) * KK + qs0 * 8;
    const u16* pAl1 = pAl0 + (size_t)128 * KK;
    const u16* pBh0 = Bhi + (col0 + sr0) * KK + qs0 * 8;
    const u16* pBh1 = pBh0 + (size_t)128 * KK;
    const u16* pBl0 = Blo + (col0 + sr0) * KK + qs0 * 8;
    const u16* pBl1 = pBl0 + (size_t)128 * KK;

#define STG_A(bw, k) { u16* db = (u16*)sh + (bw) * 32768 + tid * 8;            \
        gl16(pAh0 + (k), db);            gl16(pAh1 + (k), db + 4096);          \
        if constexpr (!SGL) {                                                  \
            gl16(pAl0 + (k), db + 8192); gl16(pAl1 + (k), db + 12288); } }
#define STG_B(bw, k) { u16* db = (u16*)sh + (bw) * 32768 + 16384 + tid * 8;    \
        gl16(pBh0 + (k), db);            gl16(pBh1 + (k), db + 4096);          \
        if constexpr (!SGL) {                                                  \
            gl16(pBl0 + (k), db + 8192); gl16(pBl1 + (k), db + 12288); } }

    const int rA = wm * 128 + l15;
    const int rB = wn * 64 + l15;
    const int aoff = rA * 32 + (((lane >> 4) ^ ((rA >> 1) & 3)) * 8);
    const int boff = rB * 32 + (((lane >> 4) ^ ((rB >> 1) & 3)) * 8);

    f32x4 acc[8][4] = {};

    STG_A(0, 0);
    STG_B(0, 0);
    __syncthreads();

    int cur = 0;
    for (int kt = 0; kt < 32; ++kt) {
        const int kn = (kt + 1) * 32;
        const u16* br = (const u16*)sh + cur * 32768;
        const int bw = cur ^ 1;
        const bool st = kt < 31;

        if constexpr (SGL) {
            // ---- barrier-light: stage t+1, read all frags, 32 MFMA ----
            if (st) { STG_A(bw, kn); STG_B(bw, kn); }
            s8v bhf[4];
#pragma unroll
            for (int ni = 0; ni < 4; ++ni)
                bhf[ni] = *(const s8v*)(br + 16384 + boff + ni * 512);
            s8v ahf[8];
#pragma unroll
            for (int mi = 0; mi < 8; ++mi)
                ahf[mi] = *(const s8v*)(br + aoff + mi * 512);
            __builtin_amdgcn_s_setprio(1);
#pragma unroll
            for (int mi = 0; mi < 8; ++mi)
#pragma unroll
                for (int ni = 0; ni < 4; ++ni)
                    acc[mi][ni] = __builtin_amdgcn_mfma_f32_16x16x32_bf16(ahf[mi], bhf[ni], acc[mi][ni], 0, 0, 0);
            __builtin_amdgcn_s_setprio(0);
            __syncthreads();
            cur ^= 1;
            continue;
        }

        // ---- hi/lo path: R13 4-phase schedule (unchanged) ----
        if (st) STG_A(bw, kn);
        s8v bhf[4], blf[4];
#pragma unroll
        for (int ni = 0; ni < 4; ++ni) {
            bhf[ni] = *(const s8v*)(br + 16384 + boff + ni * 512);
            blf[ni] = *(const s8v*)(br + 24576 + boff + ni * 512);
        }
        {
            s8v ah0 = *(const s8v*)(br + aoff);
            s8v al0 = *(const s8v*)(br + 8192 + aoff);
            s8v ah1 = *(const s8v*)(br + aoff + 512);
            s8v al1 = *(const s8v*)(br + 8192 + aoff + 512);
            __builtin_amdgcn_s_setprio(1);
#pragma unroll
            for (int ni = 0; ni < 4; ++ni) {
                acc[0][ni] = __builtin_amdgcn_mfma_f32_16x16x32_bf16(ah0, bhf[ni], acc[0][ni], 0, 0, 0);
                acc[0][ni] = __builtin_amdgcn_mfma_f32_16x16x32_bf16(ah0, blf[ni], acc[0][ni], 0, 0, 0);
                acc[0][ni] = __builtin_amdgcn_mfma_f32_16x16x32_bf16(al0, bhf[ni], acc[0][ni], 0, 0, 0);
                acc[1][ni] = __builtin_amdgcn_mfma_f32_16x16x32_bf16(ah1, bhf[ni], acc[1][ni], 0, 0, 0);
                acc[1][ni] = __builtin_amdgcn_mfma_f32_16x16x32_bf16(ah1, blf[ni], acc[1][ni], 0, 0, 0);
                acc[1][ni] = __builtin_amdgcn_mfma_f32_16x16x32_bf16(al1, bhf[ni], acc[1][ni], 0, 0, 0);
            }
            __builtin_amdgcn_s_setprio(0);
        }
        __builtin_amdgcn_s_barrier();

#pragma unroll
        for (int p = 1; p < 4; ++p) {
            if (p == 1 && st) STG_B(bw, kn);
            const int m0 = 2 * p;
            s8v ah0 = *(const s8v*)(br + aoff + m0 * 512);
            s8v al0 = *(const s8v*)(br + 8192 + aoff + m0 * 512);
            s8v ah1 = *(const s8v*)(br + aoff + (m0 + 1) * 512);
            s8v al1 = *(const s8v*)(br + 8192 + aoff + (m0 + 1) * 512);
            __builtin_amdgcn_s_setprio(1);
#pragma unroll
            for (int ni = 0; ni < 4; ++ni) {
                acc[m0][ni] = __builtin_amdgcn_mfma_f32_16x16x32_bf16(ah0, bhf[ni], acc[m0][ni], 0, 0, 0);
                acc[m0][ni] = __builtin_amdgcn_mfma_f32_16x16x32_bf16(ah0, blf[ni], acc[m0][ni], 0, 0, 0);
                acc[m0][ni] = __builtin_amdgcn_mfma_f32_16x16x32_bf16(al0, bhf[ni], acc[m0][ni], 0, 0, 0);
                acc[m0 + 1][ni] = __builtin_amdgcn_mfma_f32_16x16x32_bf16(ah1, bhf[ni], acc[m0 + 1][ni], 0, 0, 0);
                acc[m0 + 1][ni] = __builtin_amdgcn_mfma_f32_16x16x32_bf16(ah1, blf[ni], acc[m0 + 1][ni], 0, 0, 0);
                acc[m0 + 1][ni] = __builtin_amdgcn_mfma_f32_16x16x32_bf16(al1, bhf[ni], acc[m0 + 1][ni], 0, 0, 0);
            }
            __builtin_amdgcn_s_setprio(0);
            if (p < 3) __builtin_amdgcn_s_barrier();
        }

        __syncthreads();
        cur ^= 1;
    }
#undef STG_A
#undef STG_B

    const int fr = (lane >> 4) * 4;
    const int fc = lane & 15;

    if constexpr (OUT == 2) {
#pragma unroll
        for (int mi = 0; mi < 8; ++mi)
#pragma unroll
            for (int ni = 0; ni < 4; ++ni) {
                size_t rbase = row0 + wm * 128 + mi * 16 + fr;
                size_t cidx = col0 + wn * 64 + ni * 16 + fc;
#pragma unroll
                for (int g = 0; g < 4; ++g) {
                    float o = acc[mi][ni][g];
                    u16 h = f2bf(o);
                    size_t idx = (rbase + g) * 1024 + cidx;
                    Ohi[idx] = h;
                    if constexpr (!SGL) {
                        Olo[idx] = f2bf(o - bf2f(h));
                    }
                }
            }
    } else {
        float bj[4];
#pragma unroll
        for (int ni = 0; ni < 4; ++ni) bj[ni] = bias[col0 + wn * 64 + ni * 16 + fc];
#pragma unroll
        for (int mi = 0; mi < 8; ++mi)
#pragma unroll
            for (int ni = 0; ni < 4; ++ni) {
                size_t rbase = row0 + wm * 128 + mi * 16 + fr;
                size_t cidx = col0 + wn * 64 + ni * 16 + fc;
#pragma unroll
                for (int g = 0; g < 4; ++g)
                    C[(rbase + g) * (size_t)ldc + cidx] = acc[mi][ni][g] + bj[ni];
            }
    }
}

// ---------------- fused MFMA attention (R17, unchanged) --------------------
__global__ __launch_bounds__(256) void fattn_k(const u16* __restrict__ Qhi,
                                               const u16* __restrict__ Khi,
                                               const u16* __restrict__ Vthi,
                                               const u16* __restrict__ Vtlo,
                                               const float2* __restrict__ tab,
                                               u16* __restrict__ Phi,
                                               u16* __restrict__ Plo) {
    __shared__ u16 qh[64 * 64];      // 8 KB  [tok][unit^(tok&7) * 8]
    __shared__ u16 zb[16 * 512];     // 16 KB [(w*4+cf)*512 + lane*8 + e]
    __shared__ float lpart[4][64];
    __shared__ float invl[64];

    const int tid = threadIdx.x;
    const int lane = tid & 63;
    const int w = tid >> 6;
    const int g = lane >> 4;
    const int l15 = lane & 15;
    const int hh = blockIdx.y, bb = blockIdx.z;
    const int bh = bb * 16 + hh;
    const int tok0 = blockIdx.x * 64;

    // ---- stage Q into LDS (source pre-swizzled; dest linear) ----
#pragma unroll
    for (int i = 0; i < 2; ++i) {
        int ulin = tid + 256 * i;          // tok*8 + u'
        int tok = ulin >> 3, up = ulin & 7;
        size_t src = ((size_t)(bb * NN + tok0 + tok)) * 1024 + hh * 64
                     + ((up ^ (tok & 7)) << 3);
        gl16(Qhi + src, qh + ulin * 8);
    }
    __syncthreads();

    const size_t kbase = (size_t)bh * NCL * 64;
    const size_t vbase = (size_t)bh * 64 * 256;
    const int dg = w * 16 + l15;

    float lp[4] = {0.f, 0.f, 0.f, 0.f};
    f32x4 oacc[4] = {};

#pragma unroll
    for (int h = 0; h < 2; ++h) {
        // ---- QK^T for f in {2h, 2h+1} (single-bf16 both operands) ----
        f32x4 acch[2][4] = {};
#pragma unroll
        for (int ff = 0; ff < 2; ++ff) {
            const int f = 2 * h + ff;
            const int cl = w * 64 + f * 16 + l15;
            s8v kf[2];
#pragma unroll
            for (int ks = 0; ks < 2; ++ks) {
                size_t ko = kbase + (size_t)cl * 64 + (((ks * 4 + g) ^ (l15 & 7)) << 3);
                kf[ks] = *(const s8v*)(Khi + ko);
            }
#pragma unroll
            for (int cf = 0; cf < 4; ++cf) {
                const int qr = cf * 16 + l15;   // token row in LDS
#pragma unroll
                for (int ks = 0; ks < 2; ++ks) {
                    int qa = qr * 64 + (((ks * 4 + g) ^ (qr & 7)) << 3);
                    s8v qfh = *(const s8v*)&qh[qa];
                    acch[ff][cf] = __builtin_amdgcn_mfma_f32_16x16x32_bf16(kf[ks], qfh, acch[ff][cf], 0, 0, 0);
                }
            }
        }

        // ---- softmax weights -> read-linear z (single RNE bf16) ----
#pragma unroll
        for (int ff = 0; ff < 2; ++ff) {
            const int f = 2 * h + ff;
            float2 t4[4];
#pragma unroll
            for (int r = 0; r < 4; ++r)
                t4[r] = tab[bb * NCL + w * 64 + f * 16 + 4 * g + r];
#pragma unroll
            for (int cf = 0; cf < 4; ++cf) {
                float z[4];
#pragma unroll
                for (int r = 0; r < 4; ++r) {
                    float e = __expf(acch[ff][cf][r] * t4[r].x);
                    lp[cf] += t4[r].y * e;
                    z[r] = t4[r].y > 0.f ? e : 0.f;
                }
                uint2 pz;
                pz.x = (unsigned int)f2bf(z[0]) | ((unsigned int)f2bf(z[1]) << 16);
                pz.y = (unsigned int)f2bf(z[2]) | ((unsigned int)f2bf(z[3]) << 16);
                int a16 = (w * 4 + cf) * 512
                          + ((2 * ff + (g >> 1)) * 16 + l15) * 8 + 4 * (g & 1);
                *(uint2*)&zb[a16] = pz;
            }
        }

        if (h == 1) {
#pragma unroll
            for (int cf = 0; cf < 4; ++cf) {
                float v = lp[cf];
                v += __shfl_xor(v, 16);
                v += __shfl_xor(v, 32);
                lp[cf] = v;
            }
            if (lane < 16) {
#pragma unroll
                for (int cf = 0; cf < 4; ++cf) lpart[w][cf * 16 + lane] = lp[cf];
            }
        }
        __syncthreads();   // z half ready (h=1: + lpart ready)

        if (h == 1 && w == 0)
            invl[lane] = 1.f / (lpart[0][lane] + lpart[1][lane] + lpart[2][lane] + lpart[3][lane]);

        // ---- PV for this half: ks = 2s+h, z chunk = s*4+cf (2 MFMA) ----
#pragma unroll
        for (int s = 0; s < 4; ++s) {
            int kst = 2 * s + h;
            size_t vo = vbase + (size_t)dg * 256
                        + (((kst * 4 + g) & 24) | (((kst * 4 + g) ^ dg) & 7)) * 8;
            s8v vh = *(const s8v*)(Vthi + vo);
            s8v vl = *(const s8v*)(Vtlo + vo);
#pragma unroll
            for (int cf = 0; cf < 4; ++cf) {
                int a16 = (s * 4 + cf) * 512 + lane * 8;
                s8v zf = *(const s8v*)&zb[a16];
                oacc[cf] = __builtin_amdgcn_mfma_f32_16x16x32_bf16(vh, zf, oacc[cf], 0, 0, 0);
                oacc[cf] = __builtin_amdgcn_mfma_f32_16x16x32_bf16(vl, zf, oacc[cf], 0, 0, 0);
            }
        }
        __syncthreads();   // z reads done (h=0) / invl ready (h=1)
    }

    // ---- epilogue: scale by 1/l, trunc hi/lo pack, store ----
#pragma unroll
    for (int cf = 0; cf < 4; ++cf) {
        const int tokL = cf * 16 + l15;
        float il = invl[tokL];
        float o0 = oacc[cf][0] * il, o1 = oacc[cf][1] * il;
        float o2 = oacc[cf][2] * il, o3 = oacc[cf][3] * il;
        unsigned int b0 = __float_as_uint(o0), b1 = __float_as_uint(o1);
        unsigned int b2 = __float_as_uint(o2), b3 = __float_as_uint(o3);
        float r0 = o0 - __uint_as_float(b0 & 0xFFFF0000u);
        float r1 = o1 - __uint_as_float(b1 & 0xFFFF0000u);
        float r2 = o2 - __uint_as_float(b2 & 0xFFFF0000u);
        float r3 = o3 - __uint_as_float(b3 & 0xFFFF0000u);
        uint2 ph, pl;
        ph.x = pk2hi(b0, b1); ph.y = pk2hi(b2, b3);
        pl.x = pk2hi(__float_as_uint(r0), __float_as_uint(r1));
        pl.y = pk2hi(__float_as_uint(r2), __float_as_uint(r3));
        size_t po = ((size_t)(bb * NN + tok0 + tokL)) * 1024 + hh * 64 + w * 16 + 4 * g;
        *(uint2*)(Phi + po) = ph;
        *(uint2*)(Plo + po) = pl;
    }
}

// ---------------- launcher -------------------------------------------------
extern "C" void kernel_launch(void* const* d_in, const int* in_sizes, int n_in,
                              void* d_out, int out_size, void* d_ws, size_t ws_size,
                              hipStream_t stream) {
    const int* cluster  = (const int*)d_in[0];
    const float* x      = (const float*)d_in[1];
    const float* w_q    = (const float*)d_in[2];
    const float* w_kv   = (const float*)d_in[3];
    const float* w_proj = (const float*)d_in[4];
    const float* b_proj = (const float*)d_in[5];
    float* out = (float*)d_out;

    // layout (~312 MiB)
    const size_t SZ_H  = (size_t)MM * 1024 * 2;      // 64 MiB
    const size_t SZ_W  = (size_t)4096 * 1024 * 2;    // 8 MiB
    const size_t SZ_XS = (size_t)2048 * 1024 * 2;    // 4 MiB
    const size_t SZ_CS = (size_t)2048 * 2048 * 4;    // 16 MiB
    const size_t SZ_KV = (size_t)128 * NCL * 64 * 2; // 4 MiB

    char* p = (char*)d_ws;
    u16* Xhi = (u16*)p;   p += SZ_H;    // Phi (fattn out / out-proj A hi)
    u16* Xlo = (u16*)p;   p += SZ_H;    // Plo
    u16* Qhi = (u16*)p;   p += SZ_H;
    u16* Qlo = (u16*)p;   p += SZ_H;    // unused (layout stability)
    u16* Wthi = (u16*)p;  p += SZ_W;
    u16* Wtlo = (u16*)p;  p += SZ_W;
    u16* XShi = (u16*)p;  p += SZ_XS;
    u16* XSlo = (u16*)p;  p += SZ_XS;
    float* Csum = (float*)p; p += SZ_CS;
    u16* Khi = (u16*)p;   p += SZ_KV;
    u16* Klo = (u16*)p;   p += SZ_KV;   // unused
    u16* Vthi = (u16*)p;  p += SZ_KV;
    u16* Vtlo = (u16*)p;  p += SZ_KV;
    float2* tab = (float2*)p; p += 2048 * sizeof(float2);
    int* counts = (int*)p;   p += 2048 * sizeof(int);
    int* tokidx = (int*)p;   p += (size_t)BB * NN * sizeof(int);
    int* starts = (int*)p;
    (void)Klo; (void)Qlo;

    // fused prologue: prep (8) | convw3 (6144) | convx1 (32768) — concurrent
    prologue_k<<<8 + 6144 + 32768, 256, 0, stream>>>(
        cluster, counts, tab, tokidx, starts,
        x, Xhi, w_q, w_kv, w_proj, Wthi, Wtlo);

    xsum2_k<<<BB * NCL, 256, 0, stream>>>(x, tokidx, starts, counts, XShi, XSlo);

    // Q = X @ Wq^T (single-bf16 score path, barrier-light) -> Qhi
    hgemm256_k<2, 1><<<512, 512, 0, stream>>>(Xhi, Xlo, Wthi, Wtlo,
                                              nullptr, 0, nullptr, Qhi, Qlo);
    // Csum = XS @ Wkv^T (ksum | vsum), fp32 (full hi/lo: V path)
    hgemm_k<0><<<dim3(16, 16), 256, 0, stream>>>(XShi, XSlo,
                                                 Wthi + (size_t)1024 * KK, Wtlo + (size_t)1024 * KK,
                                                 Csum, 2048, nullptr, nullptr, nullptr);
    // K (single bf16) + V^T (hi/lo), fused conversion
    convkv_k<<<128, 256, 0, stream>>>(Csum, Khi, Vthi, Vtlo);

    // fused attention -> P (bf16 hi/lo, aliases X buffers); 64-tok blocks
    fattn_k<<<dim3(NN / 64, HEADS, BB), 256, 0, stream>>>(Qhi, Khi,
                                                          Vthi, Vtlo, tab, Xhi, Xlo);
    // out = P @ Wproj^T + bias (full hi/lo: R13 4-phase schedule)
    hgemm256_k<1, 0><<<512, 512, 0, stream>>>(Xhi, Xlo,
                                              Wthi + (size_t)3072 * KK, Wtlo + (size_t)3072 * KK,
                                              out, 1024, b_proj, nullptr, nullptr);
}